// Round 2
// baseline (333.152 us; speedup 1.0000x reference)
//
#include <hip/hip_runtime.h>
#include <hip/hip_bf16.h>
#include <math.h>

typedef __attribute__((ext_vector_type(4))) float f32x4;
typedef __attribute__((ext_vector_type(8))) short s16x8;

#define B_    16
#define L_    4096
#define D_    64
#define QB    64
#define KVB   64
#define NW    4

// 0.125 (1/sqrt(64)) * log2(e), folded into Q so softmax is pure exp2
#define QSCALE 0.18033688011112042f

__device__ __forceinline__ unsigned short f2bf(float x) {
  union { float f; unsigned u; } v; v.f = x;
  unsigned r = v.u + 0x7FFFu + ((v.u >> 16) & 1u);
  return (unsigned short)(r >> 16);
}

__device__ __forceinline__ int swz(int x) {
  return ((x & 7) ^ ((x >> 3) & 7)) << 4;
}

__device__ __forceinline__ void gload_lds16(const void* g, void* l) {
  __builtin_amdgcn_global_load_lds(
      (const __attribute__((address_space(1))) void*)g,
      (__attribute__((address_space(3))) void*)l, 16, 0, 0);
}

// ---------------------------------------------------------------------------
// Prepass: K -> bf16 swizzled tile images; V -> bf16 transposed swizzled images.
// One 8KB image per (batch, 64-key tile), laid out exactly as the main
// kernel's LDS buffer so staging is a plain linear global_load_lds copy.
// ---------------------------------------------------------------------------
__global__ __launch_bounds__(256) void prep_kv(
    const float* __restrict__ Kg, const float* __restrict__ Vg,
    unsigned short* __restrict__ Kw, unsigned short* __restrict__ Vw) {
  const int tid = threadIdx.x;
  const int blk = blockIdx.x;     // b*64 + tile
  const int skey2 = (tid >> 3) * 2;
  const int sdseg = tid & 7;

  const float* kp0 = Kg + ((size_t)blk * KVB + skey2) * D_ + sdseg * 8;
  const float* vp0 = Vg + ((size_t)blk * KVB + skey2) * D_ + sdseg * 8;
  char* kout = (char*)(Kw + (size_t)blk * (KVB * D_));
  char* vout = (char*)(Vw + (size_t)blk * (KVB * D_));

  // K rows: [key][d] swizzled
#pragma unroll
  for (int q2 = 0; q2 < 2; ++q2) {
    const int key = skey2 + q2;
    f32x4 a0 = *(const f32x4*)(kp0 + q2 * D_);
    f32x4 a1 = *(const f32x4*)(kp0 + q2 * D_ + 4);
    s16x8 w;
#pragma unroll
    for (int i = 0; i < 4; ++i) {
      w[i]     = (short)f2bf(a0[i]);
      w[i + 4] = (short)f2bf(a1[i]);
    }
    *(s16x8*)(kout + ((key * 128 + sdseg * 16) ^ swz(key))) = w;
  }

  // V transposed: [d][key] swizzled
  f32x4 v0 = *(const f32x4*)(vp0);
  f32x4 v1 = *(const f32x4*)(vp0 + 4);
  f32x4 v2 = *(const f32x4*)(vp0 + D_);
  f32x4 v3 = *(const f32x4*)(vp0 + D_ + 4);
#pragma unroll
  for (int u = 0; u < 2; ++u) {
#pragma unroll
    for (int i = 0; i < 4; ++i) {
      const int d = sdseg * 8 + u * 4 + i;
      unsigned lo = (unsigned)f2bf(u ? v1[i] : v0[i]);
      unsigned hi = (unsigned)f2bf(u ? v3[i] : v2[i]);
      *(unsigned*)(vout + ((d * 128 + skey2 * 2) ^ swz(d))) = lo | (hi << 16);
    }
  }
}

// ---------------------------------------------------------------------------
// Main flash-attention kernel: stages pre-converted bf16 tiles via
// global_load_lds (linear copy of the pre-swizzled image).
// ---------------------------------------------------------------------------
__global__ __launch_bounds__(256) void attn_fwd2(
    const float* __restrict__ Qg, const unsigned short* __restrict__ Kw,
    const unsigned short* __restrict__ Vw, float* __restrict__ Og) {
  __shared__ unsigned short Ks[KVB * D_];
  __shared__ unsigned short Vs[D_ * KVB];
  __shared__ unsigned short Ps[NW][16 * KVB];

  const int tid  = threadIdx.x;
  const int wv   = tid >> 6;
  const int lane = tid & 63;
  const int rl   = lane & 15;
  const int kb   = lane >> 4;

  const int blk = blockIdx.x;
  const int b   = blk / (L_ / QB);
  const int qt  = blk % (L_ / QB);

  // Q fragments with QSCALE folded in: A[row=rl][k = h*32 + kb*8 + j]
  const float* qrow_p = Qg + ((size_t)b * L_ + qt * QB + wv * 16 + rl) * D_;
  s16x8 aq[2];
#pragma unroll
  for (int h = 0; h < 2; ++h) {
    const float* p = qrow_p + h * 32 + kb * 8;
    f32x4 x0 = *(const f32x4*)p;
    f32x4 x1 = *(const f32x4*)(p + 4);
    s16x8 w;
#pragma unroll
    for (int i = 0; i < 4; ++i) {
      w[i]     = (short)f2bf(x0[i] * QSCALE);
      w[i + 4] = (short)f2bf(x1[i] * QSCALE);
    }
    aq[h] = w;
  }

  f32x4 oacc[4];
  float m_r[4], l_r[4];
#pragma unroll
  for (int t = 0; t < 4; ++t) oacc[t] = (f32x4){0.f, 0.f, 0.f, 0.f};
#pragma unroll
  for (int j = 0; j < 4; ++j) { m_r[j] = -3.0e38f; l_r[j] = 0.f; }

  const char* ksrc = (const char*)(Kw + (size_t)b * L_ * D_);
  const char* vsrc = (const char*)(Vw + (size_t)b * L_ * D_);

  char* ksc = (char*)Ks;
  char* vsc = (char*)Vs;
  char* psc = (char*)(Ps[wv]);

  const int lane16 = lane * 16;
  const int woff   = wv * 2048;

  for (int kv = 0; kv < L_ / KVB; ++kv) {
    __syncthreads();
    // ---- stage: linear 8KB image copies, direct to LDS ----
    {
      const char* kt = ksrc + (size_t)kv * 8192;
      const char* vt = vsrc + (size_t)kv * 8192;
#pragma unroll
      for (int c = 0; c < 2; ++c) {
        const int off = woff + c * 1024;
        gload_lds16(kt + off + lane16, ksc + off);
        gload_lds16(vt + off + lane16, vsc + off);
      }
    }
    __syncthreads();

    // ---- S = Q K^T (already in log2-scaled domain via QSCALE) ----
    f32x4 s[4];
#pragma unroll
    for (int t = 0; t < 4; ++t) {
      const int key  = t * 16 + rl;
      const int base = key * 128 + kb * 16;
      s16x8 b0 = *(const s16x8*)(ksc + ((base)      ^ swz(key)));
      s16x8 b1 = *(const s16x8*)(ksc + ((base + 64) ^ swz(key)));
      f32x4 acc = (f32x4){0.f, 0.f, 0.f, 0.f};
      acc = __builtin_amdgcn_mfma_f32_16x16x32_bf16(aq[0], b0, acc, 0, 0, 0);
      acc = __builtin_amdgcn_mfma_f32_16x16x32_bf16(aq[1], b1, acc, 0, 0, 0);
      s[t] = acc;
    }

    // ---- zero-score mask (reference fidelity) ----
#pragma unroll
    for (int t = 0; t < 4; ++t)
#pragma unroll
      for (int j = 0; j < 4; ++j)
        if (s[t][j] == 0.0f) s[t][j] = -1e30f;

    // ---- online softmax (base-2 domain) ----
    float alpha[4];
#pragma unroll
    for (int j = 0; j < 4; ++j) {
      float mx = fmaxf(fmaxf(s[0][j], s[1][j]), fmaxf(s[2][j], s[3][j]));
      mx = fmaxf(mx, __shfl_xor(mx, 1));
      mx = fmaxf(mx, __shfl_xor(mx, 2));
      mx = fmaxf(mx, __shfl_xor(mx, 4));
      mx = fmaxf(mx, __shfl_xor(mx, 8));
      const float mn = fmaxf(m_r[j], mx);
      alpha[j] = exp2f(m_r[j] - mn);
      m_r[j]   = mn;
    }

    float rs[4] = {0.f, 0.f, 0.f, 0.f};
#pragma unroll
    for (int t = 0; t < 4; ++t)
#pragma unroll
      for (int j = 0; j < 4; ++j) {
        const float p = exp2f(s[t][j] - m_r[j]);
        rs[j] += p;
        const int row = kb * 4 + j;
        *(unsigned short*)(psc + ((row * 128 + (t * 16 + rl) * 2) ^ swz(row))) = f2bf(p);
      }
#pragma unroll
    for (int j = 0; j < 4; ++j) l_r[j] = l_r[j] * alpha[j] + rs[j];

#pragma unroll
    for (int t = 0; t < 4; ++t)
#pragma unroll
      for (int j = 0; j < 4; ++j) oacc[t][j] *= alpha[j];

    // ---- O += P V ----
    s16x8 ap[2];
#pragma unroll
    for (int h = 0; h < 2; ++h) {
      const int base = rl * 128 + h * 64 + kb * 16;
      ap[h] = *(const s16x8*)(psc + (base ^ swz(rl)));
    }
#pragma unroll
    for (int t = 0; t < 4; ++t) {
      const int d    = t * 16 + rl;
      const int base = d * 128 + kb * 16;
      s16x8 bv0 = *(const s16x8*)(vsc + ((base)      ^ swz(d)));
      s16x8 bv1 = *(const s16x8*)(vsc + ((base + 64) ^ swz(d)));
      f32x4 acc = oacc[t];
      acc = __builtin_amdgcn_mfma_f32_16x16x32_bf16(ap[0], bv0, acc, 0, 0, 0);
      acc = __builtin_amdgcn_mfma_f32_16x16x32_bf16(ap[1], bv1, acc, 0, 0, 0);
      oacc[t] = acc;
    }
  }

  float inv[4];
#pragma unroll
  for (int j = 0; j < 4; ++j) {
    float r = l_r[j];
    r += __shfl_xor(r, 1);
    r += __shfl_xor(r, 2);
    r += __shfl_xor(r, 4);
    r += __shfl_xor(r, 8);
    inv[j] = 1.0f / r;
  }
  float* op = Og + ((size_t)b * L_ + qt * QB + wv * 16 + kb * 4) * D_;
#pragma unroll
  for (int j = 0; j < 4; ++j)
#pragma unroll
    for (int t = 0; t < 4; ++t)
      op[(size_t)j * D_ + t * 16 + rl] = oacc[t][j] * inv[j];
}

// ---------------------------------------------------------------------------
// Fallback (round-1 kernel) if the workspace is too small for the prepass.
// ---------------------------------------------------------------------------
__global__ __launch_bounds__(256) void attn_fwd_fb(
    const float* __restrict__ Qg, const float* __restrict__ Kg,
    const float* __restrict__ Vg, float* __restrict__ Og) {
  __shared__ unsigned short Ks[KVB * D_];
  __shared__ unsigned short Vs[D_ * KVB];
  __shared__ unsigned short Ps[NW][16 * KVB];

  const int tid  = threadIdx.x;
  const int wv   = tid >> 6;
  const int lane = tid & 63;
  const int rl   = lane & 15;
  const int kb   = lane >> 4;

  const int blk = blockIdx.x;
  const int b   = blk / (L_ / QB);
  const int qt  = blk % (L_ / QB);

  const float* qrow_p = Qg + ((size_t)b * L_ + qt * QB + wv * 16 + rl) * D_;
  s16x8 aq[2];
#pragma unroll
  for (int h = 0; h < 2; ++h) {
    const float* p = qrow_p + h * 32 + kb * 8;
    f32x4 x0 = *(const f32x4*)p;
    f32x4 x1 = *(const f32x4*)(p + 4);
    s16x8 w;
#pragma unroll
    for (int i = 0; i < 4; ++i) {
      w[i]     = (short)f2bf(x0[i] * QSCALE);
      w[i + 4] = (short)f2bf(x1[i] * QSCALE);
    }
    aq[h] = w;
  }

  f32x4 oacc[4];
  float m_r[4], l_r[4];
#pragma unroll
  for (int t = 0; t < 4; ++t) oacc[t] = (f32x4){0.f, 0.f, 0.f, 0.f};
#pragma unroll
  for (int j = 0; j < 4; ++j) { m_r[j] = -3.0e38f; l_r[j] = 0.f; }

  const float* kb_p = Kg + (size_t)b * L_ * D_;
  const float* vb_p = Vg + (size_t)b * L_ * D_;
  const int skey2 = (tid >> 3) * 2;
  const int sdseg = tid & 7;

  char* ksc = (char*)Ks;
  char* vsc = (char*)Vs;
  char* psc = (char*)(Ps[wv]);

  for (int kv = 0; kv < L_; kv += KVB) {
    __syncthreads();
    {
      const float* kp0 = kb_p + (size_t)(kv + skey2) * D_ + sdseg * 8;
      const float* vp0 = vb_p + (size_t)(kv + skey2) * D_ + sdseg * 8;
#pragma unroll
      for (int q2 = 0; q2 < 2; ++q2) {
        const int key = skey2 + q2;
        f32x4 a0 = *(const f32x4*)(kp0 + q2 * D_);
        f32x4 a1 = *(const f32x4*)(kp0 + q2 * D_ + 4);
        s16x8 w;
#pragma unroll
        for (int i = 0; i < 4; ++i) {
          w[i]     = (short)f2bf(a0[i]);
          w[i + 4] = (short)f2bf(a1[i]);
        }
        *(s16x8*)(ksc + ((key * 128 + sdseg * 16) ^ swz(key))) = w;
      }
      f32x4 v0 = *(const f32x4*)(vp0);
      f32x4 v1 = *(const f32x4*)(vp0 + 4);
      f32x4 v2 = *(const f32x4*)(vp0 + D_);
      f32x4 v3 = *(const f32x4*)(vp0 + D_ + 4);
#pragma unroll
      for (int u = 0; u < 2; ++u) {
#pragma unroll
        for (int i = 0; i < 4; ++i) {
          const int d = sdseg * 8 + u * 4 + i;
          unsigned lo = (unsigned)f2bf(u ? v1[i] : v0[i]);
          unsigned hi = (unsigned)f2bf(u ? v3[i] : v2[i]);
          *(unsigned*)(vsc + ((d * 128 + skey2 * 2) ^ swz(d))) = lo | (hi << 16);
        }
      }
    }
    __syncthreads();

    f32x4 s[4];
#pragma unroll
    for (int t = 0; t < 4; ++t) {
      const int key  = t * 16 + rl;
      const int base = key * 128 + kb * 16;
      s16x8 b0 = *(const s16x8*)(ksc + ((base)      ^ swz(key)));
      s16x8 b1 = *(const s16x8*)(ksc + ((base + 64) ^ swz(key)));
      f32x4 acc = (f32x4){0.f, 0.f, 0.f, 0.f};
      acc = __builtin_amdgcn_mfma_f32_16x16x32_bf16(aq[0], b0, acc, 0, 0, 0);
      acc = __builtin_amdgcn_mfma_f32_16x16x32_bf16(aq[1], b1, acc, 0, 0, 0);
      s[t] = acc;
    }

#pragma unroll
    for (int t = 0; t < 4; ++t)
#pragma unroll
      for (int j = 0; j < 4; ++j)
        if (s[t][j] == 0.0f) s[t][j] = -1e30f;

    float alpha[4];
#pragma unroll
    for (int j = 0; j < 4; ++j) {
      float mx = fmaxf(fmaxf(s[0][j], s[1][j]), fmaxf(s[2][j], s[3][j]));
      mx = fmaxf(mx, __shfl_xor(mx, 1));
      mx = fmaxf(mx, __shfl_xor(mx, 2));
      mx = fmaxf(mx, __shfl_xor(mx, 4));
      mx = fmaxf(mx, __shfl_xor(mx, 8));
      const float mn = fmaxf(m_r[j], mx);
      alpha[j] = exp2f(m_r[j] - mn);
      m_r[j]   = mn;
    }

    float rs[4] = {0.f, 0.f, 0.f, 0.f};
#pragma unroll
    for (int t = 0; t < 4; ++t)
#pragma unroll
      for (int j = 0; j < 4; ++j) {
        const float p = exp2f(s[t][j] - m_r[j]);
        rs[j] += p;
        const int row = kb * 4 + j;
        *(unsigned short*)(psc + ((row * 128 + (t * 16 + rl) * 2) ^ swz(row))) = f2bf(p);
      }
#pragma unroll
    for (int j = 0; j < 4; ++j) l_r[j] = l_r[j] * alpha[j] + rs[j];

#pragma unroll
    for (int t = 0; t < 4; ++t)
#pragma unroll
      for (int j = 0; j < 4; ++j) oacc[t][j] *= alpha[j];

    s16x8 ap[2];
#pragma unroll
    for (int h = 0; h < 2; ++h) {
      const int base = rl * 128 + h * 64 + kb * 16;
      ap[h] = *(const s16x8*)(psc + (base ^ swz(rl)));
    }
#pragma unroll
    for (int t = 0; t < 4; ++t) {
      const int d    = t * 16 + rl;
      const int base = d * 128 + kb * 16;
      s16x8 bv0 = *(const s16x8*)(vsc + ((base)      ^ swz(d)));
      s16x8 bv1 = *(const s16x8*)(vsc + ((base + 64) ^ swz(d)));
      f32x4 acc = oacc[t];
      acc = __builtin_amdgcn_mfma_f32_16x16x32_bf16(ap[0], bv0, acc, 0, 0, 0);
      acc = __builtin_amdgcn_mfma_f32_16x16x32_bf16(ap[1], bv1, acc, 0, 0, 0);
      oacc[t] = acc;
    }
  }

  float inv[4];
#pragma unroll
  for (int j = 0; j < 4; ++j) {
    float r = l_r[j];
    r += __shfl_xor(r, 1);
    r += __shfl_xor(r, 2);
    r += __shfl_xor(r, 4);
    r += __shfl_xor(r, 8);
    inv[j] = 1.0f / r;
  }
  float* op = Og + ((size_t)b * L_ + qt * QB + wv * 16 + kb * 4) * D_;
#pragma unroll
  for (int j = 0; j < 4; ++j)
#pragma unroll
    for (int t = 0; t < 4; ++t)
      op[(size_t)j * D_ + t * 16 + rl] = oacc[t][j] * inv[j];
}

extern "C" void kernel_launch(void* const* d_in, const int* in_sizes, int n_in,
                              void* d_out, int out_size, void* d_ws, size_t ws_size,
                              hipStream_t stream) {
  (void)in_sizes; (void)n_in; (void)out_size;
  const float* Q = (const float*)d_in[0];
  const float* K = (const float*)d_in[1];
  const float* V = (const float*)d_in[2];
  float* O = (float*)d_out;

  const size_t need = (size_t)2 * B_ * L_ * D_ * sizeof(unsigned short);  // 16 MB
  if (d_ws != nullptr && ws_size >= need) {
    unsigned short* Kw = (unsigned short*)d_ws;
    unsigned short* Vw = Kw + (size_t)B_ * L_ * D_;
    prep_kv<<<dim3(B_ * (L_ / KVB)), 256, 0, stream>>>(K, V, Kw, Vw);
    attn_fwd2<<<dim3(B_ * (L_ / QB)), 256, 0, stream>>>(Q, Kw, Vw, O);
  } else {
    attn_fwd_fb<<<dim3(B_ * (L_ / QB)), 256, 0, stream>>>(Q, K, V, O);
  }
}

// Round 3
// 201.861 us; speedup vs baseline: 1.6504x; 1.6504x over previous
//
#include <hip/hip_runtime.h>
#include <hip/hip_bf16.h>
#include <math.h>

typedef __attribute__((ext_vector_type(4))) float f32x4;
typedef __attribute__((ext_vector_type(8))) short s16x8;

#define B_    16
#define L_    4096
#define D_    64
#define QB    64
#define KVB   64
#define NT    (L_ / KVB)

// 0.125 (1/sqrt(64)) * log2(e), folded into Q so softmax is pure exp2
#define QSCALE 0.18033688011112042f
#define THR    8.0f

__device__ __forceinline__ unsigned short f2bf(float x) {
  union { float f; unsigned u; } v; v.f = x;
  unsigned r = v.u + 0x7FFFu + ((v.u >> 16) & 1u);
  return (unsigned short)(r >> 16);
}

__device__ __forceinline__ int swz(int x) {
  return ((x & 7) ^ ((x >> 3) & 7)) << 4;
}

__device__ __forceinline__ void gload_lds16(const void* g, void* l) {
  __builtin_amdgcn_global_load_lds(
      (const __attribute__((address_space(1))) void*)g,
      (__attribute__((address_space(3))) void*)l, 16, 0, 0);
}

__device__ __forceinline__ unsigned cvtpk_bf16(float lo, float hi) {
  unsigned r;
  asm("v_cvt_pk_bf16_f32 %0, %1, %2" : "=v"(r) : "v"(lo), "v"(hi));
  return r;
}

__device__ __forceinline__ void pl32_swap(unsigned& a, unsigned& b) {
#if __has_builtin(__builtin_amdgcn_permlane32_swap)
  auto r = __builtin_amdgcn_permlane32_swap(a, b, false, false);
  a = r[0]; b = r[1];
#else
  asm volatile("v_permlane32_swap_b32 %0, %1" : "+v"(a), "+v"(b));
#endif
}

__device__ __forceinline__ void pl16_swap(unsigned& a, unsigned& b) {
#if __has_builtin(__builtin_amdgcn_permlane16_swap)
  auto r = __builtin_amdgcn_permlane16_swap(a, b, false, false);
  a = r[0]; b = r[1];
#else
  asm volatile("v_permlane16_swap_b32 %0, %1" : "+v"(a), "+v"(b));
#endif
}

__device__ __forceinline__ float fexp2(float x) {
#if __has_builtin(__builtin_amdgcn_exp2f)
  return __builtin_amdgcn_exp2f(x);
#else
  return exp2f(x);
#endif
}

// ---------------------------------------------------------------------------
// Prepass: K -> bf16 swizzled tile images; V -> bf16 transposed swizzled
// images. Build image in LDS, then write coalesced 16B to global.
// ---------------------------------------------------------------------------
__global__ __launch_bounds__(256) void prep_kv2(
    const float* __restrict__ Kg, const float* __restrict__ Vg,
    unsigned short* __restrict__ Kw, unsigned short* __restrict__ Vw) {
  __shared__ unsigned short kim[KVB * D_];
  __shared__ unsigned short vim[KVB * D_];
  const int tid = threadIdx.x;
  const int blk = blockIdx.x;     // b*64 + tile
  const int skey2 = (tid >> 3) * 2;
  const int sdseg = tid & 7;

  const float* kp0 = Kg + ((size_t)blk * KVB + skey2) * D_ + sdseg * 8;
  const float* vp0 = Vg + ((size_t)blk * KVB + skey2) * D_ + sdseg * 8;
  char* kimc = (char*)kim;
  char* vimc = (char*)vim;

  // K rows: [key][d] swizzled
#pragma unroll
  for (int q2 = 0; q2 < 2; ++q2) {
    const int key = skey2 + q2;
    f32x4 a0 = *(const f32x4*)(kp0 + q2 * D_);
    f32x4 a1 = *(const f32x4*)(kp0 + q2 * D_ + 4);
    union { s16x8 v; unsigned w[4]; } t_;
    t_.w[0] = cvtpk_bf16(a0[0], a0[1]);
    t_.w[1] = cvtpk_bf16(a0[2], a0[3]);
    t_.w[2] = cvtpk_bf16(a1[0], a1[1]);
    t_.w[3] = cvtpk_bf16(a1[2], a1[3]);
    *(s16x8*)(kimc + ((key * 128 + sdseg * 16) ^ swz(key))) = t_.v;
  }

  // V transposed: [d][key] swizzled
  f32x4 v0 = *(const f32x4*)(vp0);
  f32x4 v1 = *(const f32x4*)(vp0 + 4);
  f32x4 v2 = *(const f32x4*)(vp0 + D_);
  f32x4 v3 = *(const f32x4*)(vp0 + D_ + 4);
#pragma unroll
  for (int u = 0; u < 2; ++u) {
#pragma unroll
    for (int i = 0; i < 4; ++i) {
      const int d = sdseg * 8 + u * 4 + i;
      unsigned pk = cvtpk_bf16(u ? v1[i] : v0[i], u ? v3[i] : v2[i]);
      *(unsigned*)(vimc + ((d * 128 + skey2 * 2) ^ swz(d))) = pk;
    }
  }
  __syncthreads();

  // coalesced 16B copy to global
  char* kd = (char*)(Kw + (size_t)blk * (KVB * D_));
  char* vd = (char*)(Vw + (size_t)blk * (KVB * D_));
#pragma unroll
  for (int c = 0; c < 2; ++c) {
    const int off = c * 4096 + tid * 16;
    *(s16x8*)(kd + off) = *(const s16x8*)(kimc + off);
    *(s16x8*)(vd + off) = *(const s16x8*)(vimc + off);
  }
}

// ---------------------------------------------------------------------------
// Main flash-attention kernel: swapped QK^T (lane-local softmax rows),
// in-register P via cvt_pk + permlane swaps, defer-max rescale,
// double-buffered K/V staging via global_load_lds.
// ---------------------------------------------------------------------------
__global__ __launch_bounds__(256) void attn_fwd3(
    const float* __restrict__ Qg, const unsigned short* __restrict__ Kw,
    const unsigned short* __restrict__ Vw, float* __restrict__ Og) {
  __shared__ unsigned short Ks[2][KVB * D_];   // 2 x 8KB
  __shared__ unsigned short Vs[2][KVB * D_];   // 2 x 8KB

  const int tid  = threadIdx.x;
  const int wv   = tid >> 6;
  const int lane = tid & 63;
  const int rl   = lane & 15;   // q-row (softmax) / A-frag row
  const int kb   = lane >> 4;
  const int kb4  = kb * 4;

  const int blk = blockIdx.x;
  const int b   = blk >> 6;      // L_/QB = 64
  const int qt  = blk & 63;

  // ---- Q B-frag with QSCALE folded: B[k = h*32 + kb*8 + j][col = rl] ----
  const float* qrow_p = Qg + ((size_t)b * L_ + qt * QB + wv * 16 + rl) * D_;
  s16x8 aq[2];
#pragma unroll
  for (int h = 0; h < 2; ++h) {
    const float* p = qrow_p + h * 32 + kb * 8;
    f32x4 x0 = *(const f32x4*)p;
    f32x4 x1 = *(const f32x4*)(p + 4);
    union { s16x8 v; unsigned w[4]; } t_;
    t_.w[0] = cvtpk_bf16(x0[0] * QSCALE, x0[1] * QSCALE);
    t_.w[1] = cvtpk_bf16(x0[2] * QSCALE, x0[3] * QSCALE);
    t_.w[2] = cvtpk_bf16(x1[0] * QSCALE, x1[1] * QSCALE);
    t_.w[3] = cvtpk_bf16(x1[2] * QSCALE, x1[3] * QSCALE);
    aq[h] = t_.v;
  }

  // ---- loop-invariant LDS read offsets ----
  int koffA[4], koffB[4], voffA[4], voffB[4];
#pragma unroll
  for (int t = 0; t < 4; ++t) {
    const int key = t * 16 + rl;
    const int kbase = key * 128 + kb * 16;
    koffA[t] = kbase ^ swz(key);
    koffB[t] = (kbase + 64) ^ swz(key);
    const int d  = t * 16 + rl;
    const int vb = d * 128 + kb * 16;
    voffA[t] = vb ^ swz(d);
    voffB[t] = (vb + 64) ^ swz(d);
  }

  f32x4 oacc[4];
#pragma unroll
  for (int t = 0; t < 4; ++t) oacc[t] = (f32x4){0.f, 0.f, 0.f, 0.f};
  float m_r = -3.0e38f, l_r = 0.f;

  const char* ksrc = (const char*)(Kw + (size_t)b * L_ * D_);
  const char* vsrc = (const char*)(Vw + (size_t)b * L_ * D_);
  char* ks0 = (char*)(&Ks[0][0]);
  char* vs0 = (char*)(&Vs[0][0]);
  const int woff   = wv * 2048;
  const int lane16 = lane * 16;

  // ---- prologue: stage tile 0 -> buffer 0 ----
  {
    const char* kt = ksrc + woff + lane16;
    const char* vt = vsrc + woff + lane16;
    gload_lds16(kt,        ks0 + woff);
    gload_lds16(kt + 1024, ks0 + woff + 1024);
    gload_lds16(vt,        vs0 + woff);
    gload_lds16(vt + 1024, vs0 + woff + 1024);
  }
  __syncthreads();

#pragma unroll 2
  for (int kv = 0; kv < NT; ++kv) {
    const int boff  = (kv & 1) * 8192;
    const int nboff = 8192 - boff;

    // ---- issue next tile's staging (lands before the barrier below) ----
    if (kv + 1 < NT) {
      const char* kt = ksrc + (size_t)(kv + 1) * 8192 + woff + lane16;
      const char* vt = vsrc + (size_t)(kv + 1) * 8192 + woff + lane16;
      gload_lds16(kt,        ks0 + nboff + woff);
      gload_lds16(kt + 1024, ks0 + nboff + woff + 1024);
      gload_lds16(vt,        vs0 + nboff + woff);
      gload_lds16(vt + 1024, vs0 + nboff + woff + 1024);
    }

    const char* kbase = ks0 + boff;
    const char* vbase = vs0 + boff;

    // ---- S' = K Q^T: lane holds S[key=t*16+kb4+j][qrow=rl] ----
    f32x4 s[4];
#pragma unroll
    for (int t = 0; t < 4; ++t) {
      s16x8 k0 = *(const s16x8*)(kbase + koffA[t]);
      s16x8 k1 = *(const s16x8*)(kbase + koffB[t]);
      f32x4 acc = (f32x4){0.f, 0.f, 0.f, 0.f};
      acc = __builtin_amdgcn_mfma_f32_16x16x32_bf16(k0, aq[0], acc, 0, 0, 0);
      acc = __builtin_amdgcn_mfma_f32_16x16x32_bf16(k1, aq[1], acc, 0, 0, 0);
      s[t] = acc;
    }

    // ---- zero-score mask (reference fidelity) ----
#pragma unroll
    for (int t = 0; t < 4; ++t)
#pragma unroll
      for (int j = 0; j < 4; ++j)
        s[t][j] = (s[t][j] == 0.0f) ? -1e30f : s[t][j];

    // ---- lane-local max over this lane's 16 keys ----
    float mx = s[0][0];
#pragma unroll
    for (int t = 0; t < 4; ++t)
#pragma unroll
      for (int j = 0; j < 4; ++j) mx = fmaxf(mx, s[t][j]);

    // ---- defer-max: rescale only when some row grew by > THR ----
    if (__any(mx > m_r + THR)) {
      float rmx = fmaxf(mx, __shfl_xor(mx, 16));
      rmx = fmaxf(rmx, __shfl_xor(rmx, 32));
      const float mn = fmaxf(m_r, rmx);
      const float alpha = fexp2(m_r - mn);   // first iter: exp2(-huge) = 0
      m_r = mn;
      l_r *= alpha;
      const float a0 = __shfl(alpha, kb4 + 0);
      const float a1 = __shfl(alpha, kb4 + 1);
      const float a2 = __shfl(alpha, kb4 + 2);
      const float a3 = __shfl(alpha, kb4 + 3);
#pragma unroll
      for (int t = 0; t < 4; ++t) {
        oacc[t][0] *= a0; oacc[t][1] *= a1;
        oacc[t][2] *= a2; oacc[t][3] *= a3;
      }
    }

    // ---- P = exp2(S - m), lane-partial l ----
    float p[4][4];
    float rs = 0.f;
#pragma unroll
    for (int t = 0; t < 4; ++t)
#pragma unroll
      for (int j = 0; j < 4; ++j) {
        const float e = fexp2(s[t][j] - m_r);
        p[t][j] = e;
        rs += e;
      }
    l_r += rs;

    // ---- pack P to bf16 and permute into the PV A-fragment ----
    unsigned Wp[4][2];
#pragma unroll
    for (int t = 0; t < 4; ++t) {
      Wp[t][0] = cvtpk_bf16(p[t][0], p[t][1]);
      Wp[t][1] = cvtpk_bf16(p[t][2], p[t][3]);
    }
    union { s16x8 v; unsigned w[4]; } AF0, AF1;
    {
      unsigned x = Wp[0][0], y = Wp[1][0];
      pl32_swap(x, y); pl16_swap(x, y);
      AF0.w[0] = x; AF0.w[2] = y;
    }
    {
      unsigned x = Wp[0][1], y = Wp[1][1];
      pl32_swap(x, y); pl16_swap(x, y);
      AF0.w[1] = x; AF0.w[3] = y;
    }
    {
      unsigned x = Wp[2][0], y = Wp[3][0];
      pl32_swap(x, y); pl16_swap(x, y);
      AF1.w[0] = x; AF1.w[2] = y;
    }
    {
      unsigned x = Wp[2][1], y = Wp[3][1];
      pl32_swap(x, y); pl16_swap(x, y);
      AF1.w[1] = x; AF1.w[3] = y;
    }

    // ---- O += P V ----
#pragma unroll
    for (int t = 0; t < 4; ++t) {
      s16x8 bv0 = *(const s16x8*)(vbase + voffA[t]);
      s16x8 bv1 = *(const s16x8*)(vbase + voffB[t]);
      f32x4 acc = oacc[t];
      acc = __builtin_amdgcn_mfma_f32_16x16x32_bf16(AF0.v, bv0, acc, 0, 0, 0);
      acc = __builtin_amdgcn_mfma_f32_16x16x32_bf16(AF1.v, bv1, acc, 0, 0, 0);
      oacc[t] = acc;
    }

    __syncthreads();   // drains vmcnt: next tile staged; this buffer free
  }

  // ---- epilogue: reduce l across kb lanes, normalize, store fp32 ----
  float lt = l_r + __shfl_xor(l_r, 16);
  lt += __shfl_xor(lt, 32);
  const float linv = 1.0f / lt;
  const float i0 = __shfl(linv, kb4 + 0);
  const float i1 = __shfl(linv, kb4 + 1);
  const float i2 = __shfl(linv, kb4 + 2);
  const float i3 = __shfl(linv, kb4 + 3);
  float inv[4] = {i0, i1, i2, i3};

  float* op = Og + ((size_t)b * L_ + qt * QB + wv * 16 + kb4) * D_;
#pragma unroll
  for (int j = 0; j < 4; ++j)
#pragma unroll
    for (int t = 0; t < 4; ++t)
      op[(size_t)j * D_ + t * 16 + rl] = oacc[t][j] * inv[j];
}

// ---------------------------------------------------------------------------
// Fallback (round-1 style) if the workspace is too small for the prepass.
// ---------------------------------------------------------------------------
__global__ __launch_bounds__(256) void attn_fwd_fb(
    const float* __restrict__ Qg, const float* __restrict__ Kg,
    const float* __restrict__ Vg, float* __restrict__ Og) {
  __shared__ unsigned short Ksf[KVB * D_];
  __shared__ unsigned short Vsf[KVB * D_];
  __shared__ unsigned short Psf[4][16 * KVB];

  const int tid  = threadIdx.x;
  const int wv   = tid >> 6;
  const int lane = tid & 63;
  const int rl   = lane & 15;
  const int kb   = lane >> 4;

  const int blk = blockIdx.x;
  const int b   = blk / (L_ / QB);
  const int qt  = blk % (L_ / QB);

  const float* qrow_p = Qg + ((size_t)b * L_ + qt * QB + wv * 16 + rl) * D_;
  s16x8 aq[2];
#pragma unroll
  for (int h = 0; h < 2; ++h) {
    const float* p = qrow_p + h * 32 + kb * 8;
    f32x4 x0 = *(const f32x4*)p;
    f32x4 x1 = *(const f32x4*)(p + 4);
    s16x8 w;
#pragma unroll
    for (int i = 0; i < 4; ++i) {
      w[i]     = (short)f2bf(x0[i] * QSCALE);
      w[i + 4] = (short)f2bf(x1[i] * QSCALE);
    }
    aq[h] = w;
  }

  f32x4 oacc[4];
  float m_r[4], l_r[4];
#pragma unroll
  for (int t = 0; t < 4; ++t) oacc[t] = (f32x4){0.f, 0.f, 0.f, 0.f};
#pragma unroll
  for (int j = 0; j < 4; ++j) { m_r[j] = -3.0e38f; l_r[j] = 0.f; }

  const float* kb_p = Kg + (size_t)b * L_ * D_;
  const float* vb_p = Vg + (size_t)b * L_ * D_;
  const int skey2 = (tid >> 3) * 2;
  const int sdseg = tid & 7;

  char* ksc = (char*)Ksf;
  char* vsc = (char*)Vsf;
  char* psc = (char*)(Psf[wv]);

  for (int kv = 0; kv < L_; kv += KVB) {
    __syncthreads();
    {
      const float* kp0 = kb_p + (size_t)(kv + skey2) * D_ + sdseg * 8;
      const float* vp0 = vb_p + (size_t)(kv + skey2) * D_ + sdseg * 8;
#pragma unroll
      for (int q2 = 0; q2 < 2; ++q2) {
        const int key = skey2 + q2;
        f32x4 a0 = *(const f32x4*)(kp0 + q2 * D_);
        f32x4 a1 = *(const f32x4*)(kp0 + q2 * D_ + 4);
        s16x8 w;
#pragma unroll
        for (int i = 0; i < 4; ++i) {
          w[i]     = (short)f2bf(a0[i]);
          w[i + 4] = (short)f2bf(a1[i]);
        }
        *(s16x8*)(ksc + ((key * 128 + sdseg * 16) ^ swz(key))) = w;
      }
      f32x4 v0 = *(const f32x4*)(vp0);
      f32x4 v1 = *(const f32x4*)(vp0 + 4);
      f32x4 v2 = *(const f32x4*)(vp0 + D_);
      f32x4 v3 = *(const f32x4*)(vp0 + D_ + 4);
#pragma unroll
      for (int u = 0; u < 2; ++u) {
#pragma unroll
        for (int i = 0; i < 4; ++i) {
          const int d = sdseg * 8 + u * 4 + i;
          unsigned lo = (unsigned)f2bf(u ? v1[i] : v0[i]);
          unsigned hi = (unsigned)f2bf(u ? v3[i] : v2[i]);
          *(unsigned*)(vsc + ((d * 128 + skey2 * 2) ^ swz(d))) = lo | (hi << 16);
        }
      }
    }
    __syncthreads();

    f32x4 s[4];
#pragma unroll
    for (int t = 0; t < 4; ++t) {
      const int key  = t * 16 + rl;
      const int base = key * 128 + kb * 16;
      s16x8 b0 = *(const s16x8*)(ksc + ((base)      ^ swz(key)));
      s16x8 b1 = *(const s16x8*)(ksc + ((base + 64) ^ swz(key)));
      f32x4 acc = (f32x4){0.f, 0.f, 0.f, 0.f};
      acc = __builtin_amdgcn_mfma_f32_16x16x32_bf16(aq[0], b0, acc, 0, 0, 0);
      acc = __builtin_amdgcn_mfma_f32_16x16x32_bf16(aq[1], b1, acc, 0, 0, 0);
      s[t] = acc;
    }

#pragma unroll
    for (int t = 0; t < 4; ++t)
#pragma unroll
      for (int j = 0; j < 4; ++j)
        if (s[t][j] == 0.0f) s[t][j] = -1e30f;

    float alpha[4];
#pragma unroll
    for (int j = 0; j < 4; ++j) {
      float mx = fmaxf(fmaxf(s[0][j], s[1][j]), fmaxf(s[2][j], s[3][j]));
      mx = fmaxf(mx, __shfl_xor(mx, 1));
      mx = fmaxf(mx, __shfl_xor(mx, 2));
      mx = fmaxf(mx, __shfl_xor(mx, 4));
      mx = fmaxf(mx, __shfl_xor(mx, 8));
      const float mn = fmaxf(m_r[j], mx);
      alpha[j] = fexp2(m_r[j] - mn);
      m_r[j]   = mn;
    }

    float rs[4] = {0.f, 0.f, 0.f, 0.f};
#pragma unroll
    for (int t = 0; t < 4; ++t)
#pragma unroll
      for (int j = 0; j < 4; ++j) {
        const float p = fexp2(s[t][j] - m_r[j]);
        rs[j] += p;
        const int row = kb * 4 + j;
        *(unsigned short*)(psc + ((row * 128 + (t * 16 + rl) * 2) ^ swz(row))) = f2bf(p);
      }
#pragma unroll
    for (int j = 0; j < 4; ++j) l_r[j] = l_r[j] * alpha[j] + rs[j];

#pragma unroll
    for (int t = 0; t < 4; ++t)
#pragma unroll
      for (int j = 0; j < 4; ++j) oacc[t][j] *= alpha[j];

    s16x8 ap[2];
#pragma unroll
    for (int h = 0; h < 2; ++h) {
      const int base = rl * 128 + h * 64 + kb * 16;
      ap[h] = *(const s16x8*)(psc + (base ^ swz(rl)));
    }
#pragma unroll
    for (int t = 0; t < 4; ++t) {
      const int d    = t * 16 + rl;
      const int base = d * 128 + kb * 16;
      s16x8 bv0 = *(const s16x8*)(vsc + ((base)      ^ swz(d)));
      s16x8 bv1 = *(const s16x8*)(vsc + ((base + 64) ^ swz(d)));
      f32x4 acc = oacc[t];
      acc = __builtin_amdgcn_mfma_f32_16x16x32_bf16(ap[0], bv0, acc, 0, 0, 0);
      acc = __builtin_amdgcn_mfma_f32_16x16x32_bf16(ap[1], bv1, acc, 0, 0, 0);
      oacc[t] = acc;
    }
  }

  float inv[4];
#pragma unroll
  for (int j = 0; j < 4; ++j) {
    float r = l_r[j];
    r += __shfl_xor(r, 1);
    r += __shfl_xor(r, 2);
    r += __shfl_xor(r, 4);
    r += __shfl_xor(r, 8);
    inv[j] = 1.0f / r;
  }
  float* op = Og + ((size_t)b * L_ + qt * QB + wv * 16 + kb * 4) * D_;
#pragma unroll
  for (int j = 0; j < 4; ++j)
#pragma unroll
    for (int t = 0; t < 4; ++t)
      op[(size_t)j * D_ + t * 16 + rl] = oacc[t][j] * inv[j];
}

extern "C" void kernel_launch(void* const* d_in, const int* in_sizes, int n_in,
                              void* d_out, int out_size, void* d_ws, size_t ws_size,
                              hipStream_t stream) {
  (void)in_sizes; (void)n_in; (void)out_size;
  const float* Q = (const float*)d_in[0];
  const float* K = (const float*)d_in[1];
  const float* V = (const float*)d_in[2];
  float* O = (float*)d_out;

  const size_t need = (size_t)2 * B_ * L_ * D_ * sizeof(unsigned short);  // 16 MB
  if (d_ws != nullptr && ws_size >= need) {
    unsigned short* Kw = (unsigned short*)d_ws;
    unsigned short* Vw = Kw + (size_t)B_ * L_ * D_;
    prep_kv2<<<dim3(B_ * (L_ / KVB)), 256, 0, stream>>>(K, V, Kw, Vw);
    attn_fwd3<<<dim3(B_ * (L_ / QB)), 256, 0, stream>>>(Q, Kw, Vw, O);
  } else {
    attn_fwd_fb<<<dim3(B_ * (L_ / QB)), 256, 0, stream>>>(Q, K, V, O);
  }
}

// Round 4
// 196.960 us; speedup vs baseline: 1.6915x; 1.0249x over previous
//
#include <hip/hip_runtime.h>
#include <hip/hip_bf16.h>
#include <math.h>

typedef __attribute__((ext_vector_type(4))) float f32x4;
typedef __attribute__((ext_vector_type(8))) short s16x8;

#define B_    16
#define L_    4096
#define D_    64
#define QB    64
#define KVB   64
#define NT    (L_ / KVB)

// 0.125 (1/sqrt(64)) * log2(e), folded into Q so softmax is pure exp2
#define QSCALE 0.18033688011112042f
#define THR    8.0f

__device__ __forceinline__ unsigned short f2bf(float x) {
  union { float f; unsigned u; } v; v.f = x;
  unsigned r = v.u + 0x7FFFu + ((v.u >> 16) & 1u);
  return (unsigned short)(r >> 16);
}

__device__ __forceinline__ int swz(int x) {
  return ((x & 7) ^ ((x >> 3) & 7)) << 4;
}

__device__ __forceinline__ void gload_lds16(const void* g, void* l) {
  __builtin_amdgcn_global_load_lds(
      (const __attribute__((address_space(1))) void*)g,
      (__attribute__((address_space(3))) void*)l, 16, 0, 0);
}

__device__ __forceinline__ unsigned cvtpk_bf16(float lo, float hi) {
  unsigned r;
  asm("v_cvt_pk_bf16_f32 %0, %1, %2" : "=v"(r) : "v"(lo), "v"(hi));
  return r;
}

__device__ __forceinline__ void pl32_swap(unsigned& a, unsigned& b) {
#if __has_builtin(__builtin_amdgcn_permlane32_swap)
  auto r = __builtin_amdgcn_permlane32_swap(a, b, false, false);
  a = r[0]; b = r[1];
#else
  asm volatile("v_permlane32_swap_b32 %0, %1" : "+v"(a), "+v"(b));
#endif
}

__device__ __forceinline__ void pl16_swap(unsigned& a, unsigned& b) {
#if __has_builtin(__builtin_amdgcn_permlane16_swap)
  auto r = __builtin_amdgcn_permlane16_swap(a, b, false, false);
  a = r[0]; b = r[1];
#else
  asm volatile("v_permlane16_swap_b32 %0, %1" : "+v"(a), "+v"(b));
#endif
}

__device__ __forceinline__ float fexp2(float x) {
#if __has_builtin(__builtin_amdgcn_exp2f)
  return __builtin_amdgcn_exp2f(x);
#else
  return exp2f(x);
#endif
}

// ---------------------------------------------------------------------------
// Prepass: 2048 blocks. blk<1024: K bf16 swizzled image (16B stores).
// blk>=1024: V bf16 transposed swizzled image (4B pair stores).
// Direct global stores, no LDS, no barrier.
// ---------------------------------------------------------------------------
__global__ __launch_bounds__(256) void prep_kv3(
    const float* __restrict__ Kg, const float* __restrict__ Vg,
    unsigned short* __restrict__ Kw, unsigned short* __restrict__ Vw) {
  const int tid = threadIdx.x;
  int blk = blockIdx.x;
  if (blk < B_ * NT) {
    // ---- K image ----
    const float* src = Kg + (size_t)blk * (KVB * D_);
    char* dst = (char*)(Kw + (size_t)blk * (KVB * D_));
#pragma unroll
    for (int c = 0; c < 2; ++c) {
      const int ch  = tid + c * 256;   // 0..511
      const int key = ch >> 3;
      const int seg = ch & 7;
      const float* p = src + key * D_ + seg * 8;
      f32x4 x0 = *(const f32x4*)p;
      f32x4 x1 = *(const f32x4*)(p + 4);
      union { s16x8 v; unsigned w[4]; } t_;
      t_.w[0] = cvtpk_bf16(x0[0], x0[1]);
      t_.w[1] = cvtpk_bf16(x0[2], x0[3]);
      t_.w[2] = cvtpk_bf16(x1[0], x1[1]);
      t_.w[3] = cvtpk_bf16(x1[2], x1[3]);
      *(s16x8*)(dst + ((key * 128 + seg * 16) ^ swz(key))) = t_.v;
    }
  } else {
    // ---- V transposed image ----
    blk -= B_ * NT;
    const int skey2 = (tid >> 3) * 2;
    const int sdseg = tid & 7;
    const float* vp0 = Vg + ((size_t)blk * KVB + skey2) * D_ + sdseg * 8;
    char* vout = (char*)(Vw + (size_t)blk * (KVB * D_));
    f32x4 v0 = *(const f32x4*)(vp0);
    f32x4 v1 = *(const f32x4*)(vp0 + 4);
    f32x4 v2 = *(const f32x4*)(vp0 + D_);
    f32x4 v3 = *(const f32x4*)(vp0 + D_ + 4);
#pragma unroll
    for (int u = 0; u < 2; ++u) {
#pragma unroll
      for (int i = 0; i < 4; ++i) {
        const int d = sdseg * 8 + u * 4 + i;
        unsigned pk = cvtpk_bf16(u ? v1[i] : v0[i], u ? v3[i] : v2[i]);
        *(unsigned*)(vout + ((d * 128 + skey2 * 2) ^ swz(d))) = pk;
      }
    }
  }
}

// ---------------------------------------------------------------------------
// Main flash-attention kernel.
// ---------------------------------------------------------------------------
__global__ __launch_bounds__(256) void attn_fwd4(
    const float* __restrict__ Qg, const unsigned short* __restrict__ Kw,
    const unsigned short* __restrict__ Vw, float* __restrict__ Og) {
  __shared__ unsigned short Ks[2][KVB * D_];   // 2 x 8KB
  __shared__ unsigned short Vs[2][KVB * D_];   // 2 x 8KB

  const int tid  = threadIdx.x;
  const int wv   = tid >> 6;
  const int lane = tid & 63;
  const int rl   = lane & 15;   // q-row
  const int kb   = lane >> 4;
  const int kb4  = kb * 4;

  const int blk = blockIdx.x;
  const int b   = blk >> 6;      // L_/QB = 64
  const int qt  = blk & 63;

  // ---- Q B-frag with QSCALE folded ----
  const float* qrow_p = Qg + ((size_t)b * L_ + qt * QB + wv * 16 + rl) * D_;
  s16x8 aq[2];
#pragma unroll
  for (int h = 0; h < 2; ++h) {
    const float* p = qrow_p + h * 32 + kb * 8;
    f32x4 x0 = *(const f32x4*)p;
    f32x4 x1 = *(const f32x4*)(p + 4);
    union { s16x8 v; unsigned w[4]; } t_;
    t_.w[0] = cvtpk_bf16(x0[0] * QSCALE, x0[1] * QSCALE);
    t_.w[1] = cvtpk_bf16(x0[2] * QSCALE, x0[3] * QSCALE);
    t_.w[2] = cvtpk_bf16(x1[0] * QSCALE, x1[1] * QSCALE);
    t_.w[3] = cvtpk_bf16(x1[2] * QSCALE, x1[3] * QSCALE);
    aq[h] = t_.v;
  }

  // ---- loop-invariant LDS read offsets ----
  int koffA[4], koffB[4], voffA[4], voffB[4];
#pragma unroll
  for (int t = 0; t < 4; ++t) {
    const int key = t * 16 + rl;
    const int kbase = key * 128 + kb * 16;
    koffA[t] = kbase ^ swz(key);
    koffB[t] = (kbase + 64) ^ swz(key);
    voffA[t] = kbase ^ swz(key);      // same formula: d = t*16+rl
    voffB[t] = (kbase + 64) ^ swz(key);
  }

  f32x4 oacc[4];
#pragma unroll
  for (int t = 0; t < 4; ++t) oacc[t] = (f32x4){0.f, 0.f, 0.f, 0.f};
  float m_r = -3.0e38f, l_r = 0.f;

  char* ks0 = (char*)(&Ks[0][0]);
  char* vs0 = (char*)(&Vs[0][0]);
  const int woff = wv * 2048 ;
  const char* kt = (const char*)(Kw + (size_t)b * L_ * D_) + woff + lane * 16;
  const char* vt = (const char*)(Vw + (size_t)b * L_ * D_) + woff + lane * 16;

  // ---- compute one staged tile ----
  auto compute = [&](const char* kbase, const char* vbase) {
    // S' = K Q^T: lane holds S[key = t*16 + kb4 + j][qrow = rl]
    f32x4 s[4];
    __builtin_amdgcn_s_setprio(1);
#pragma unroll
    for (int t = 0; t < 4; ++t) {
      s16x8 k0 = *(const s16x8*)(kbase + koffA[t]);
      s16x8 k1 = *(const s16x8*)(kbase + koffB[t]);
      f32x4 acc = (f32x4){0.f, 0.f, 0.f, 0.f};
      acc = __builtin_amdgcn_mfma_f32_16x16x32_bf16(k0, aq[0], acc, 0, 0, 0);
      acc = __builtin_amdgcn_mfma_f32_16x16x32_bf16(k1, aq[1], acc, 0, 0, 0);
      s[t] = acc;
    }
    __builtin_amdgcn_s_setprio(0);

    // lane-local max (max3-friendly tree)
    float a0 = fmaxf(fmaxf(s[0][0], s[0][1]), s[0][2]);
    float a1 = fmaxf(fmaxf(s[0][3], s[1][0]), s[1][1]);
    float a2 = fmaxf(fmaxf(s[1][2], s[1][3]), s[2][0]);
    float a3 = fmaxf(fmaxf(s[2][1], s[2][2]), s[2][3]);
    float a4 = fmaxf(fmaxf(s[3][0], s[3][1]), s[3][2]);
    float mx = fmaxf(fmaxf(fmaxf(a0, a1), fmaxf(a2, a3)),
                     fmaxf(a4, s[3][3]));

    // defer-max: rescale only when some row grew by > THR
    if (__any(mx > m_r + THR)) {
      float rmx = fmaxf(mx, __shfl_xor(mx, 16));
      rmx = fmaxf(rmx, __shfl_xor(rmx, 32));
      const float mn = fmaxf(m_r, rmx);
      const float alpha = fexp2(m_r - mn);   // first iter: exp2(-huge) = 0
      m_r = mn;
      l_r *= alpha;
      const float b0 = __shfl(alpha, kb4 + 0);
      const float b1 = __shfl(alpha, kb4 + 1);
      const float b2 = __shfl(alpha, kb4 + 2);
      const float b3 = __shfl(alpha, kb4 + 3);
#pragma unroll
      for (int t = 0; t < 4; ++t) {
        oacc[t][0] *= b0; oacc[t][1] *= b1;
        oacc[t][2] *= b2; oacc[t][3] *= b3;
      }
    }

    // P = exp2(S - m) fused with bf16 pack; lane-partial l
    unsigned Wp[4][2];
    float rs = 0.f;
#pragma unroll
    for (int t = 0; t < 4; ++t) {
      const float e0 = fexp2(s[t][0] - m_r);
      const float e1 = fexp2(s[t][1] - m_r);
      const float e2 = fexp2(s[t][2] - m_r);
      const float e3 = fexp2(s[t][3] - m_r);
      rs += (e0 + e1) + (e2 + e3);
      Wp[t][0] = cvtpk_bf16(e0, e1);
      Wp[t][1] = cvtpk_bf16(e2, e3);
    }
    l_r += rs;

    // permute P into the PV A-fragment
    union { s16x8 v; unsigned w[4]; } AF0, AF1;
    {
      unsigned x = Wp[0][0], y = Wp[1][0];
      pl32_swap(x, y); pl16_swap(x, y);
      AF0.w[0] = x; AF0.w[2] = y;
    }
    {
      unsigned x = Wp[0][1], y = Wp[1][1];
      pl32_swap(x, y); pl16_swap(x, y);
      AF0.w[1] = x; AF0.w[3] = y;
    }
    {
      unsigned x = Wp[2][0], y = Wp[3][0];
      pl32_swap(x, y); pl16_swap(x, y);
      AF1.w[0] = x; AF1.w[2] = y;
    }
    {
      unsigned x = Wp[2][1], y = Wp[3][1];
      pl32_swap(x, y); pl16_swap(x, y);
      AF1.w[1] = x; AF1.w[3] = y;
    }

    // O += P V
    __builtin_amdgcn_s_setprio(1);
#pragma unroll
    for (int t = 0; t < 4; ++t) {
      s16x8 bv0 = *(const s16x8*)(vbase + voffA[t]);
      s16x8 bv1 = *(const s16x8*)(vbase + voffB[t]);
      f32x4 acc = oacc[t];
      acc = __builtin_amdgcn_mfma_f32_16x16x32_bf16(AF0.v, bv0, acc, 0, 0, 0);
      acc = __builtin_amdgcn_mfma_f32_16x16x32_bf16(AF1.v, bv1, acc, 0, 0, 0);
      oacc[t] = acc;
    }
    __builtin_amdgcn_s_setprio(0);
  };

  // ---- prologue: stage tile 0 -> buffer 0 ----
  gload_lds16(kt,        ks0 + woff);
  gload_lds16(kt + 1024, ks0 + woff + 1024);
  gload_lds16(vt,        vs0 + woff);
  gload_lds16(vt + 1024, vs0 + woff + 1024);
  kt += 8192; vt += 8192;
  __syncthreads();

  int boff = 0;
  for (int kv = 0; kv < NT - 1; ++kv) {
    // prefetch next tile into the other buffer
    const int nb = boff ^ 8192;
    gload_lds16(kt,        ks0 + nb + woff);
    gload_lds16(kt + 1024, ks0 + nb + woff + 1024);
    gload_lds16(vt,        vs0 + nb + woff);
    gload_lds16(vt + 1024, vs0 + nb + woff + 1024);
    kt += 8192; vt += 8192;

    compute(ks0 + boff, vs0 + boff);
    __syncthreads();   // staging done; compute buffer free
    boff = nb;
  }
  compute(ks0 + boff, vs0 + boff);   // last tile, no prefetch

  // ---- epilogue ----
  float lt = l_r + __shfl_xor(l_r, 16);
  lt += __shfl_xor(lt, 32);
  const float linv = 1.0f / lt;
  const float i0 = __shfl(linv, kb4 + 0);
  const float i1 = __shfl(linv, kb4 + 1);
  const float i2 = __shfl(linv, kb4 + 2);
  const float i3 = __shfl(linv, kb4 + 3);
  float inv[4] = {i0, i1, i2, i3};

  float* op = Og + ((size_t)b * L_ + qt * QB + wv * 16 + kb4) * D_;
#pragma unroll
  for (int j = 0; j < 4; ++j)
#pragma unroll
    for (int t = 0; t < 4; ++t)
      op[(size_t)j * D_ + t * 16 + rl] = oacc[t][j] * inv[j];
}

// ---------------------------------------------------------------------------
// Fallback (no-workspace path).
// ---------------------------------------------------------------------------
__global__ __launch_bounds__(256) void attn_fwd_fb(
    const float* __restrict__ Qg, const float* __restrict__ Kg,
    const float* __restrict__ Vg, float* __restrict__ Og) {
  __shared__ unsigned short Ksf[KVB * D_];
  __shared__ unsigned short Vsf[KVB * D_];
  __shared__ unsigned short Psf[4][16 * KVB];

  const int tid  = threadIdx.x;
  const int wv   = tid >> 6;
  const int lane = tid & 63;
  const int rl   = lane & 15;
  const int kb   = lane >> 4;

  const int blk = blockIdx.x;
  const int b   = blk / (L_ / QB);
  const int qt  = blk % (L_ / QB);

  const float* qrow_p = Qg + ((size_t)b * L_ + qt * QB + wv * 16 + rl) * D_;
  s16x8 aq[2];
#pragma unroll
  for (int h = 0; h < 2; ++h) {
    const float* p = qrow_p + h * 32 + kb * 8;
    f32x4 x0 = *(const f32x4*)p;
    f32x4 x1 = *(const f32x4*)(p + 4);
    s16x8 w;
#pragma unroll
    for (int i = 0; i < 4; ++i) {
      w[i]     = (short)f2bf(x0[i] * QSCALE);
      w[i + 4] = (short)f2bf(x1[i] * QSCALE);
    }
    aq[h] = w;
  }

  f32x4 oacc[4];
  float m_r[4], l_r[4];
#pragma unroll
  for (int t = 0; t < 4; ++t) oacc[t] = (f32x4){0.f, 0.f, 0.f, 0.f};
#pragma unroll
  for (int j = 0; j < 4; ++j) { m_r[j] = -3.0e38f; l_r[j] = 0.f; }

  const float* kb_p = Kg + (size_t)b * L_ * D_;
  const float* vb_p = Vg + (size_t)b * L_ * D_;
  const int skey2 = (tid >> 3) * 2;
  const int sdseg = tid & 7;

  char* ksc = (char*)Ksf;
  char* vsc = (char*)Vsf;
  char* psc = (char*)(Psf[wv]);

  for (int kv = 0; kv < L_; kv += KVB) {
    __syncthreads();
    {
      const float* kp0 = kb_p + (size_t)(kv + skey2) * D_ + sdseg * 8;
      const float* vp0 = vb_p + (size_t)(kv + skey2) * D_ + sdseg * 8;
#pragma unroll
      for (int q2 = 0; q2 < 2; ++q2) {
        const int key = skey2 + q2;
        f32x4 a0 = *(const f32x4*)(kp0 + q2 * D_);
        f32x4 a1 = *(const f32x4*)(kp0 + q2 * D_ + 4);
        s16x8 w;
#pragma unroll
        for (int i = 0; i < 4; ++i) {
          w[i]     = (short)f2bf(a0[i]);
          w[i + 4] = (short)f2bf(a1[i]);
        }
        *(s16x8*)(ksc + ((key * 128 + sdseg * 16) ^ swz(key))) = w;
      }
      f32x4 v0 = *(const f32x4*)(vp0);
      f32x4 v1 = *(const f32x4*)(vp0 + 4);
      f32x4 v2 = *(const f32x4*)(vp0 + D_);
      f32x4 v3 = *(const f32x4*)(vp0 + D_ + 4);
#pragma unroll
      for (int u = 0; u < 2; ++u) {
#pragma unroll
        for (int i = 0; i < 4; ++i) {
          const int d = sdseg * 8 + u * 4 + i;
          unsigned lo = (unsigned)f2bf(u ? v1[i] : v0[i]);
          unsigned hi = (unsigned)f2bf(u ? v3[i] : v2[i]);
          *(unsigned*)(vsc + ((d * 128 + skey2 * 2) ^ swz(d))) = lo | (hi << 16);
        }
      }
    }
    __syncthreads();

    f32x4 s[4];
#pragma unroll
    for (int t = 0; t < 4; ++t) {
      const int key  = t * 16 + rl;
      const int base = key * 128 + kb * 16;
      s16x8 b0 = *(const s16x8*)(ksc + ((base)      ^ swz(key)));
      s16x8 b1 = *(const s16x8*)(ksc + ((base + 64) ^ swz(key)));
      f32x4 acc = (f32x4){0.f, 0.f, 0.f, 0.f};
      acc = __builtin_amdgcn_mfma_f32_16x16x32_bf16(aq[0], b0, acc, 0, 0, 0);
      acc = __builtin_amdgcn_mfma_f32_16x16x32_bf16(aq[1], b1, acc, 0, 0, 0);
      s[t] = acc;
    }

    float alpha[4];
#pragma unroll
    for (int j = 0; j < 4; ++j) {
      float mx = fmaxf(fmaxf(s[0][j], s[1][j]), fmaxf(s[2][j], s[3][j]));
      mx = fmaxf(mx, __shfl_xor(mx, 1));
      mx = fmaxf(mx, __shfl_xor(mx, 2));
      mx = fmaxf(mx, __shfl_xor(mx, 4));
      mx = fmaxf(mx, __shfl_xor(mx, 8));
      const float mn = fmaxf(m_r[j], mx);
      alpha[j] = fexp2(m_r[j] - mn);
      m_r[j]   = mn;
    }

    float rs[4] = {0.f, 0.f, 0.f, 0.f};
#pragma unroll
    for (int t = 0; t < 4; ++t)
#pragma unroll
      for (int j = 0; j < 4; ++j) {
        const float p = fexp2(s[t][j] - m_r[j]);
        rs[j] += p;
        const int row = kb * 4 + j;
        *(unsigned short*)(psc + ((row * 128 + (t * 16 + rl) * 2) ^ swz(row))) = f2bf(p);
      }
#pragma unroll
    for (int j = 0; j < 4; ++j) l_r[j] = l_r[j] * alpha[j] + rs[j];

#pragma unroll
    for (int t = 0; t < 4; ++t)
#pragma unroll
      for (int j = 0; j < 4; ++j) oacc[t][j] *= alpha[j];

    s16x8 ap[2];
#pragma unroll
    for (int h = 0; h < 2; ++h) {
      const int base = rl * 128 + h * 64 + kb * 16;
      ap[h] = *(const s16x8*)(psc + (base ^ swz(rl)));
    }
#pragma unroll
    for (int t = 0; t < 4; ++t) {
      const int d    = t * 16 + rl;
      const int base = d * 128 + kb * 16;
      s16x8 bv0 = *(const s16x8*)(vsc + ((base)      ^ swz(d)));
      s16x8 bv1 = *(const s16x8*)(vsc + ((base + 64) ^ swz(d)));
      f32x4 acc = oacc[t];
      acc = __builtin_amdgcn_mfma_f32_16x16x32_bf16(ap[0], bv0, acc, 0, 0, 0);
      acc = __builtin_amdgcn_mfma_f32_16x16x32_bf16(ap[1], bv1, acc, 0, 0, 0);
      oacc[t] = acc;
    }
  }

  float inv[4];
#pragma unroll
  for (int j = 0; j < 4; ++j) {
    float r = l_r[j];
    r += __shfl_xor(r, 1);
    r += __shfl_xor(r, 2);
    r += __shfl_xor(r, 4);
    r += __shfl_xor(r, 8);
    inv[j] = 1.0f / r;
  }
  float* op = Og + ((size_t)b * L_ + qt * QB + wv * 16 + kb * 4) * D_;
#pragma unroll
  for (int j = 0; j < 4; ++j)
#pragma unroll
    for (int t = 0; t < 4; ++t)
      op[(size_t)j * D_ + t * 16 + rl] = oacc[t][j] * inv[j];
}

extern "C" void kernel_launch(void* const* d_in, const int* in_sizes, int n_in,
                              void* d_out, int out_size, void* d_ws, size_t ws_size,
                              hipStream_t stream) {
  (void)in_sizes; (void)n_in; (void)out_size;
  const float* Q = (const float*)d_in[0];
  const float* K = (const float*)d_in[1];
  const float* V = (const float*)d_in[2];
  float* O = (float*)d_out;

  const size_t need = (size_t)2 * B_ * L_ * D_ * sizeof(unsigned short);  // 16 MB
  if (d_ws != nullptr && ws_size >= need) {
    unsigned short* Kw = (unsigned short*)d_ws;
    unsigned short* Vw = Kw + (size_t)B_ * L_ * D_;
    prep_kv3<<<dim3(2 * B_ * NT), 256, 0, stream>>>(K, V, Kw, Vw);
    attn_fwd4<<<dim3(B_ * (L_ / QB)), 256, 0, stream>>>(Q, Kw, Vw, O);
  } else {
    attn_fwd_fb<<<dim3(B_ * (L_ / QB)), 256, 0, stream>>>(Q, K, V, O);
  }
}

// Round 5
// 193.451 us; speedup vs baseline: 1.7222x; 1.0181x over previous
//
#include <hip/hip_runtime.h>
#include <hip/hip_bf16.h>
#include <math.h>

typedef __attribute__((ext_vector_type(4))) float f32x4;
typedef __attribute__((ext_vector_type(8))) short s16x8;

#define B_    16
#define L_    4096
#define D_    64
#define QB    128          // q-rows per block (4 waves x 32)
#define KVB   64
#define NT    (L_ / KVB)

// 0.125 (1/sqrt(64)) * log2(e), folded into Q so softmax is pure exp2
#define QSCALE 0.18033688011112042f
#define THR    8.0f

__device__ __forceinline__ unsigned short f2bf(float x) {
  union { float f; unsigned u; } v; v.f = x;
  unsigned r = v.u + 0x7FFFu + ((v.u >> 16) & 1u);
  return (unsigned short)(r >> 16);
}

__device__ __forceinline__ int swz(int x) {
  return ((x & 7) ^ ((x >> 3) & 7)) << 4;
}

__device__ __forceinline__ void gload_lds16(const void* g, void* l) {
  __builtin_amdgcn_global_load_lds(
      (const __attribute__((address_space(1))) void*)g,
      (__attribute__((address_space(3))) void*)l, 16, 0, 0);
}

__device__ __forceinline__ unsigned cvtpk_bf16(float lo, float hi) {
  unsigned r;
  asm("v_cvt_pk_bf16_f32 %0, %1, %2" : "=v"(r) : "v"(lo), "v"(hi));
  return r;
}

__device__ __forceinline__ void pl32_swap(unsigned& a, unsigned& b) {
#if __has_builtin(__builtin_amdgcn_permlane32_swap)
  auto r = __builtin_amdgcn_permlane32_swap(a, b, false, false);
  a = r[0]; b = r[1];
#else
  asm volatile("v_permlane32_swap_b32 %0, %1" : "+v"(a), "+v"(b));
#endif
}

__device__ __forceinline__ void pl16_swap(unsigned& a, unsigned& b) {
#if __has_builtin(__builtin_amdgcn_permlane16_swap)
  auto r = __builtin_amdgcn_permlane16_swap(a, b, false, false);
  a = r[0]; b = r[1];
#else
  asm volatile("v_permlane16_swap_b32 %0, %1" : "+v"(a), "+v"(b));
#endif
}

__device__ __forceinline__ float fexp2(float x) {
#if __has_builtin(__builtin_amdgcn_exp2f)
  return __builtin_amdgcn_exp2f(x);
#else
  return exp2f(x);
#endif
}

// ---------------------------------------------------------------------------
// Prepass, 2048 blocks. blk<1024: K bf16 swizzled image, direct 16B stores.
// blk>=1024: V transposed swizzled image via LDS bounce (coalesced stores).
// ---------------------------------------------------------------------------
__global__ __launch_bounds__(256) void prep_kv4(
    const float* __restrict__ Kg, const float* __restrict__ Vg,
    unsigned short* __restrict__ Kw, unsigned short* __restrict__ Vw) {
  __shared__ unsigned short vim[KVB * D_];
  const int tid = threadIdx.x;
  int blk = blockIdx.x;
  if (blk < B_ * NT) {
    // ---- K image: direct, coalesced ----
    const float* src = Kg + (size_t)blk * (KVB * D_);
    char* dst = (char*)(Kw + (size_t)blk * (KVB * D_));
#pragma unroll
    for (int c = 0; c < 2; ++c) {
      const int ch  = tid + c * 256;   // 0..511
      const int key = ch >> 3;
      const int seg = ch & 7;
      const float* p = src + key * D_ + seg * 8;
      f32x4 x0 = *(const f32x4*)p;
      f32x4 x1 = *(const f32x4*)(p + 4);
      union { s16x8 v; unsigned w[4]; } t_;
      t_.w[0] = cvtpk_bf16(x0[0], x0[1]);
      t_.w[1] = cvtpk_bf16(x0[2], x0[3]);
      t_.w[2] = cvtpk_bf16(x1[0], x1[1]);
      t_.w[3] = cvtpk_bf16(x1[2], x1[3]);
      *(s16x8*)(dst + ((key * 128 + seg * 16) ^ swz(key))) = t_.v;
    }
  } else {
    // ---- V transposed image via LDS bounce ----
    blk -= B_ * NT;
    const int skey2 = (tid >> 3) * 2;
    const int sdseg = tid & 7;
    const float* vp0 = Vg + ((size_t)blk * KVB + skey2) * D_ + sdseg * 8;
    char* vimc = (char*)vim;
    f32x4 v0 = *(const f32x4*)(vp0);
    f32x4 v1 = *(const f32x4*)(vp0 + 4);
    f32x4 v2 = *(const f32x4*)(vp0 + D_);
    f32x4 v3 = *(const f32x4*)(vp0 + D_ + 4);
#pragma unroll
    for (int u = 0; u < 2; ++u) {
#pragma unroll
      for (int i = 0; i < 4; ++i) {
        const int d = sdseg * 8 + u * 4 + i;
        unsigned pk = cvtpk_bf16(u ? v1[i] : v0[i], u ? v3[i] : v2[i]);
        *(unsigned*)(vimc + ((d * 128 + skey2 * 2) ^ swz(d))) = pk;
      }
    }
    __syncthreads();
    char* vout = (char*)(Vw + (size_t)blk * (KVB * D_));
#pragma unroll
    for (int c = 0; c < 2; ++c) {
      const int off = c * 4096 + tid * 16;
      *(s16x8*)(vout + off) = *(const s16x8*)(vimc + off);
    }
  }
}

// ---------------------------------------------------------------------------
// Main kernel: 32 q-rows per wave (two 16-row halves sharing every K/V
// LDS fragment read), swapped QK^T, in-register P, defer-max, double-buffer.
// ---------------------------------------------------------------------------
__global__ __launch_bounds__(256, 2) void attn_fwd5(
    const float* __restrict__ Qg, const unsigned short* __restrict__ Kw,
    const unsigned short* __restrict__ Vw, float* __restrict__ Og) {
  __shared__ unsigned short Ks[2][KVB * D_];   // 2 x 8KB
  __shared__ unsigned short Vs[2][KVB * D_];   // 2 x 8KB

  const int tid  = threadIdx.x;
  const int wv   = tid >> 6;
  const int lane = tid & 63;
  const int rl   = lane & 15;   // q-row within half
  const int kb   = lane >> 4;
  const int kb4  = kb * 4;

  const int blk = blockIdx.x;
  const int b   = blk >> 5;      // L_/QB = 32
  const int qt  = blk & 31;

  // ---- Q B-frags for both halves, QSCALE folded ----
  const float* qbase = Qg + ((size_t)b * L_ + qt * QB + wv * 32) * D_;
  s16x8 aq0[2], aq1[2];
#pragma unroll
  for (int qh = 0; qh < 2; ++qh) {
    const float* qrow_p = qbase + (qh * 16 + rl) * D_;
#pragma unroll
    for (int h = 0; h < 2; ++h) {
      const float* p = qrow_p + h * 32 + kb * 8;
      f32x4 x0 = *(const f32x4*)p;
      f32x4 x1 = *(const f32x4*)(p + 4);
      union { s16x8 v; unsigned w[4]; } t_;
      t_.w[0] = cvtpk_bf16(x0[0] * QSCALE, x0[1] * QSCALE);
      t_.w[1] = cvtpk_bf16(x0[2] * QSCALE, x0[3] * QSCALE);
      t_.w[2] = cvtpk_bf16(x1[0] * QSCALE, x1[1] * QSCALE);
      t_.w[3] = cvtpk_bf16(x1[2] * QSCALE, x1[3] * QSCALE);
      if (qh == 0) aq0[h] = t_.v; else aq1[h] = t_.v;
    }
  }

  // ---- loop-invariant LDS read offsets (same formula for K and V) ----
  int offA[4], offB[4];
#pragma unroll
  for (int t = 0; t < 4; ++t) {
    const int row  = t * 16 + rl;
    const int base = row * 128 + kb * 16;
    offA[t] = base ^ swz(row);
    offB[t] = (base + 64) ^ swz(row);
  }

  f32x4 oacc0[4], oacc1[4];
#pragma unroll
  for (int t = 0; t < 4; ++t) {
    oacc0[t] = (f32x4){0.f, 0.f, 0.f, 0.f};
    oacc1[t] = (f32x4){0.f, 0.f, 0.f, 0.f};
  }
  float m0 = -3.0e38f, m1 = -3.0e38f, l0 = 0.f, l1 = 0.f;

  char* ks0 = (char*)(&Ks[0][0]);
  char* vs0 = (char*)(&Vs[0][0]);
  const int woff = wv * 2048;
  const char* kt = (const char*)(Kw + (size_t)b * L_ * D_) + woff + lane * 16;
  const char* vt = (const char*)(Vw + (size_t)b * L_ * D_) + woff + lane * 16;

  auto compute = [&](const char* kbase, const char* vbase) {
    // ---- S' = K Q^T for both q-halves; K frags read once ----
    f32x4 s0[4], s1[4];
    __builtin_amdgcn_s_setprio(1);
#pragma unroll
    for (int t = 0; t < 4; ++t) {
      s16x8 k0 = *(const s16x8*)(kbase + offA[t]);
      s16x8 k1 = *(const s16x8*)(kbase + offB[t]);
      f32x4 a = (f32x4){0.f, 0.f, 0.f, 0.f};
      f32x4 c = (f32x4){0.f, 0.f, 0.f, 0.f};
      a = __builtin_amdgcn_mfma_f32_16x16x32_bf16(k0, aq0[0], a, 0, 0, 0);
      c = __builtin_amdgcn_mfma_f32_16x16x32_bf16(k0, aq1[0], c, 0, 0, 0);
      a = __builtin_amdgcn_mfma_f32_16x16x32_bf16(k1, aq0[1], a, 0, 0, 0);
      c = __builtin_amdgcn_mfma_f32_16x16x32_bf16(k1, aq1[1], c, 0, 0, 0);
      s0[t] = a; s1[t] = c;
    }
    __builtin_amdgcn_s_setprio(0);

    // ---- lane-local maxima (two independent trees) ----
    float x0 = fmaxf(fmaxf(s0[0][0], s0[0][1]), fmaxf(s0[0][2], s0[0][3]));
    float x1 = fmaxf(fmaxf(s0[1][0], s0[1][1]), fmaxf(s0[1][2], s0[1][3]));
    float x2 = fmaxf(fmaxf(s0[2][0], s0[2][1]), fmaxf(s0[2][2], s0[2][3]));
    float x3 = fmaxf(fmaxf(s0[3][0], s0[3][1]), fmaxf(s0[3][2], s0[3][3]));
    float mx0 = fmaxf(fmaxf(x0, x1), fmaxf(x2, x3));
    float y0 = fmaxf(fmaxf(s1[0][0], s1[0][1]), fmaxf(s1[0][2], s1[0][3]));
    float y1 = fmaxf(fmaxf(s1[1][0], s1[1][1]), fmaxf(s1[1][2], s1[1][3]));
    float y2 = fmaxf(fmaxf(s1[2][0], s1[2][1]), fmaxf(s1[2][2], s1[2][3]));
    float y3 = fmaxf(fmaxf(s1[3][0], s1[3][1]), fmaxf(s1[3][2], s1[3][3]));
    float mx1 = fmaxf(fmaxf(y0, y1), fmaxf(y2, y3));

    // ---- defer-max rescale (rare) ----
    if (__any((mx0 > m0 + THR) || (mx1 > m1 + THR))) {
      float r0 = fmaxf(mx0, __shfl_xor(mx0, 16));
      r0 = fmaxf(r0, __shfl_xor(r0, 32));
      float r1 = fmaxf(mx1, __shfl_xor(mx1, 16));
      r1 = fmaxf(r1, __shfl_xor(r1, 32));
      const float n0 = fmaxf(m0, r0);
      const float n1 = fmaxf(m1, r1);
      const float al0 = fexp2(m0 - n0);
      const float al1 = fexp2(m1 - n1);
      m0 = n0; m1 = n1;
      l0 *= al0; l1 *= al1;
#pragma unroll
      for (int j = 0; j < 4; ++j) {
        const float b0 = __shfl(al0, kb4 + j);
        const float b1 = __shfl(al1, kb4 + j);
#pragma unroll
        for (int t = 0; t < 4; ++t) {
          oacc0[t][j] *= b0;
          oacc1[t][j] *= b1;
        }
      }
    }

    // ---- P = exp2(S - m) fused with bf16 pack ----
    unsigned W0[4][2], W1[4][2];
    float rs0 = 0.f, rs1 = 0.f;
#pragma unroll
    for (int t = 0; t < 4; ++t) {
      const float e0 = fexp2(s0[t][0] - m0);
      const float e1 = fexp2(s0[t][1] - m0);
      const float e2 = fexp2(s0[t][2] - m0);
      const float e3 = fexp2(s0[t][3] - m0);
      rs0 += (e0 + e1) + (e2 + e3);
      W0[t][0] = cvtpk_bf16(e0, e1);
      W0[t][1] = cvtpk_bf16(e2, e3);
      const float f0 = fexp2(s1[t][0] - m1);
      const float f1 = fexp2(s1[t][1] - m1);
      const float f2 = fexp2(s1[t][2] - m1);
      const float f3 = fexp2(s1[t][3] - m1);
      rs1 += (f0 + f1) + (f2 + f3);
      W1[t][0] = cvtpk_bf16(f0, f1);
      W1[t][1] = cvtpk_bf16(f2, f3);
    }
    l0 += rs0; l1 += rs1;

    // ---- permute P into PV A-fragments (per half) ----
    union { s16x8 v; unsigned w[4]; } A00, A01, A10, A11;
#pragma unroll
    for (int u = 0; u < 2; ++u) {
      { unsigned x = W0[0][u], y = W0[1][u];
        pl32_swap(x, y); pl16_swap(x, y);
        A00.w[u] = x; A00.w[u + 2] = y; }
      { unsigned x = W0[2][u], y = W0[3][u];
        pl32_swap(x, y); pl16_swap(x, y);
        A01.w[u] = x; A01.w[u + 2] = y; }
      { unsigned x = W1[0][u], y = W1[1][u];
        pl32_swap(x, y); pl16_swap(x, y);
        A10.w[u] = x; A10.w[u + 2] = y; }
      { unsigned x = W1[2][u], y = W1[3][u];
        pl32_swap(x, y); pl16_swap(x, y);
        A11.w[u] = x; A11.w[u + 2] = y; }
    }

    // ---- O += P V; V frags read once, used by both halves ----
    __builtin_amdgcn_s_setprio(1);
#pragma unroll
    for (int t = 0; t < 4; ++t) {
      s16x8 bv0 = *(const s16x8*)(vbase + offA[t]);
      s16x8 bv1 = *(const s16x8*)(vbase + offB[t]);
      f32x4 a = oacc0[t];
      f32x4 c = oacc1[t];
      a = __builtin_amdgcn_mfma_f32_16x16x32_bf16(A00.v, bv0, a, 0, 0, 0);
      c = __builtin_amdgcn_mfma_f32_16x16x32_bf16(A10.v, bv0, c, 0, 0, 0);
      a = __builtin_amdgcn_mfma_f32_16x16x32_bf16(A01.v, bv1, a, 0, 0, 0);
      c = __builtin_amdgcn_mfma_f32_16x16x32_bf16(A11.v, bv1, c, 0, 0, 0);
      oacc0[t] = a; oacc1[t] = c;
    }
    __builtin_amdgcn_s_setprio(0);
  };

  // ---- prologue: stage tile 0 -> buffer 0 ----
  gload_lds16(kt,        ks0 + woff);
  gload_lds16(kt + 1024, ks0 + woff + 1024);
  gload_lds16(vt,        vs0 + woff);
  gload_lds16(vt + 1024, vs0 + woff + 1024);
  kt += 8192; vt += 8192;
  __syncthreads();

  int boff = 0;
  for (int kv = 0; kv < NT - 1; ++kv) {
    const int nb = boff ^ 8192;
    gload_lds16(kt,        ks0 + nb + woff);
    gload_lds16(kt + 1024, ks0 + nb + woff + 1024);
    gload_lds16(vt,        vs0 + nb + woff);
    gload_lds16(vt + 1024, vs0 + nb + woff + 1024);
    kt += 8192; vt += 8192;

    compute(ks0 + boff, vs0 + boff);
    __syncthreads();
    boff = nb;
  }
  compute(ks0 + boff, vs0 + boff);

  // ---- epilogue: per-half row sums, normalize, store ----
  float t0 = l0 + __shfl_xor(l0, 16);
  t0 += __shfl_xor(t0, 32);
  float t1 = l1 + __shfl_xor(l1, 16);
  t1 += __shfl_xor(t1, 32);
  const float v0i = 1.0f / t0;
  const float v1i = 1.0f / t1;

  float* ob = Og + ((size_t)b * L_ + qt * QB + wv * 32 + kb4) * D_;
#pragma unroll
  for (int j = 0; j < 4; ++j) {
    const float i0 = __shfl(v0i, kb4 + j);
    const float i1 = __shfl(v1i, kb4 + j);
    float* r0 = ob + (size_t)j * D_;
    float* r1 = r0 + 16 * D_;
#pragma unroll
    for (int t = 0; t < 4; ++t) {
      r0[t * 16 + rl] = oacc0[t][j] * i0;
      r1[t * 16 + rl] = oacc1[t][j] * i1;
    }
  }
}

// ---------------------------------------------------------------------------
// Fallback (no-workspace path) — round-4 kernel, known-good.
// ---------------------------------------------------------------------------
__global__ __launch_bounds__(256) void attn_fwd_fb(
    const float* __restrict__ Qg, const float* __restrict__ Kg,
    const float* __restrict__ Vg, float* __restrict__ Og) {
  __shared__ unsigned short Ksf[KVB * D_];
  __shared__ unsigned short Vsf[KVB * D_];
  __shared__ unsigned short Psf[4][16 * KVB];

  const int tid  = threadIdx.x;
  const int wv   = tid >> 6;
  const int lane = tid & 63;
  const int rl   = lane & 15;
  const int kb   = lane >> 4;

  const int blk = blockIdx.x;
  const int b   = blk / (L_ / 64);
  const int qt  = blk % (L_ / 64);

  const float* qrow_p = Qg + ((size_t)b * L_ + qt * 64 + wv * 16 + rl) * D_;
  s16x8 aq[2];
#pragma unroll
  for (int h = 0; h < 2; ++h) {
    const float* p = qrow_p + h * 32 + kb * 8;
    f32x4 x0 = *(const f32x4*)p;
    f32x4 x1 = *(const f32x4*)(p + 4);
    s16x8 w;
#pragma unroll
    for (int i = 0; i < 4; ++i) {
      w[i]     = (short)f2bf(x0[i] * QSCALE);
      w[i + 4] = (short)f2bf(x1[i] * QSCALE);
    }
    aq[h] = w;
  }

  f32x4 oacc[4];
  float m_r[4], l_r[4];
#pragma unroll
  for (int t = 0; t < 4; ++t) oacc[t] = (f32x4){0.f, 0.f, 0.f, 0.f};
#pragma unroll
  for (int j = 0; j < 4; ++j) { m_r[j] = -3.0e38f; l_r[j] = 0.f; }

  const float* kb_p = Kg + (size_t)b * L_ * D_;
  const float* vb_p = Vg + (size_t)b * L_ * D_;
  const int skey2 = (tid >> 3) * 2;
  const int sdseg = tid & 7;

  char* ksc = (char*)Ksf;
  char* vsc = (char*)Vsf;
  char* psc = (char*)(Psf[wv]);

  for (int kv = 0; kv < L_; kv += KVB) {
    __syncthreads();
    {
      const float* kp0 = kb_p + (size_t)(kv + skey2) * D_ + sdseg * 8;
      const float* vp0 = vb_p + (size_t)(kv + skey2) * D_ + sdseg * 8;
#pragma unroll
      for (int q2 = 0; q2 < 2; ++q2) {
        const int key = skey2 + q2;
        f32x4 a0 = *(const f32x4*)(kp0 + q2 * D_);
        f32x4 a1 = *(const f32x4*)(kp0 + q2 * D_ + 4);
        s16x8 w;
#pragma unroll
        for (int i = 0; i < 4; ++i) {
          w[i]     = (short)f2bf(a0[i]);
          w[i + 4] = (short)f2bf(a1[i]);
        }
        *(s16x8*)(ksc + ((key * 128 + sdseg * 16) ^ swz(key))) = w;
      }
      f32x4 v0 = *(const f32x4*)(vp0);
      f32x4 v1 = *(const f32x4*)(vp0 + 4);
      f32x4 v2 = *(const f32x4*)(vp0 + D_);
      f32x4 v3 = *(const f32x4*)(vp0 + D_ + 4);
#pragma unroll
      for (int u = 0; u < 2; ++u) {
#pragma unroll
        for (int i = 0; i < 4; ++i) {
          const int d = sdseg * 8 + u * 4 + i;
          unsigned lo = (unsigned)f2bf(u ? v1[i] : v0[i]);
          unsigned hi = (unsigned)f2bf(u ? v3[i] : v2[i]);
          *(unsigned*)(vsc + ((d * 128 + skey2 * 2) ^ swz(d))) = lo | (hi << 16);
        }
      }
    }
    __syncthreads();

    f32x4 s[4];
#pragma unroll
    for (int t = 0; t < 4; ++t) {
      const int key  = t * 16 + rl;
      const int base = key * 128 + kb * 16;
      s16x8 b0 = *(const s16x8*)(ksc + ((base)      ^ swz(key)));
      s16x8 b1 = *(const s16x8*)(ksc + ((base + 64) ^ swz(key)));
      f32x4 acc = (f32x4){0.f, 0.f, 0.f, 0.f};
      acc = __builtin_amdgcn_mfma_f32_16x16x32_bf16(aq[0], b0, acc, 0, 0, 0);
      acc = __builtin_amdgcn_mfma_f32_16x16x32_bf16(aq[1], b1, acc, 0, 0, 0);
      s[t] = acc;
    }

    float alpha[4];
#pragma unroll
    for (int j = 0; j < 4; ++j) {
      float mx = fmaxf(fmaxf(s[0][j], s[1][j]), fmaxf(s[2][j], s[3][j]));
      mx = fmaxf(mx, __shfl_xor(mx, 1));
      mx = fmaxf(mx, __shfl_xor(mx, 2));
      mx = fmaxf(mx, __shfl_xor(mx, 4));
      mx = fmaxf(mx, __shfl_xor(mx, 8));
      const float mn = fmaxf(m_r[j], mx);
      alpha[j] = fexp2(m_r[j] - mn);
      m_r[j]   = mn;
    }

    float rs[4] = {0.f, 0.f, 0.f, 0.f};
#pragma unroll
    for (int t = 0; t < 4; ++t)
#pragma unroll
      for (int j = 0; j < 4; ++j) {
        const float p = fexp2(s[t][j] - m_r[j]);
        rs[j] += p;
        const int row = kb * 4 + j;
        *(unsigned short*)(psc + ((row * 128 + (t * 16 + rl) * 2) ^ swz(row))) = f2bf(p);
      }
#pragma unroll
    for (int j = 0; j < 4; ++j) l_r[j] = l_r[j] * alpha[j] + rs[j];

#pragma unroll
    for (int t = 0; t < 4; ++t)
#pragma unroll
      for (int j = 0; j < 4; ++j) oacc[t][j] *= alpha[j];

    s16x8 ap[2];
#pragma unroll
    for (int h = 0; h < 2; ++h) {
      const int base = rl * 128 + h * 64 + kb * 16;
      ap[h] = *(const s16x8*)(psc + (base ^ swz(rl)));
    }
#pragma unroll
    for (int t = 0; t < 4; ++t) {
      const int d    = t * 16 + rl;
      const int base = d * 128 + kb * 16;
      s16x8 bv0 = *(const s16x8*)(vsc + ((base)      ^ swz(d)));
      s16x8 bv1 = *(const s16x8*)(vsc + ((base + 64) ^ swz(d)));
      f32x4 acc = oacc[t];
      acc = __builtin_amdgcn_mfma_f32_16x16x32_bf16(ap[0], bv0, acc, 0, 0, 0);
      acc = __builtin_amdgcn_mfma_f32_16x16x32_bf16(ap[1], bv1, acc, 0, 0, 0);
      oacc[t] = acc;
    }
  }

  float inv[4];
#pragma unroll
  for (int j = 0; j < 4; ++j) {
    float r = l_r[j];
    r += __shfl_xor(r, 1);
    r += __shfl_xor(r, 2);
    r += __shfl_xor(r, 4);
    r += __shfl_xor(r, 8);
    inv[j] = 1.0f / r;
  }
  float* op = Og + ((size_t)b * L_ + qt * 64 + wv * 16 + kb * 4) * D_;
#pragma unroll
  for (int j = 0; j < 4; ++j)
#pragma unroll
    for (int t = 0; t < 4; ++t)
      op[(size_t)j * D_ + t * 16 + rl] = oacc[t][j] * inv[j];
}

extern "C" void kernel_launch(void* const* d_in, const int* in_sizes, int n_in,
                              void* d_out, int out_size, void* d_ws, size_t ws_size,
                              hipStream_t stream) {
  (void)in_sizes; (void)n_in; (void)out_size;
  const float* Q = (const float*)d_in[0];
  const float* K = (const float*)d_in[1];
  const float* V = (const float*)d_in[2];
  float* O = (float*)d_out;

  const size_t need = (size_t)2 * B_ * L_ * D_ * sizeof(unsigned short);  // 16 MB
  if (d_ws != nullptr && ws_size >= need) {
    unsigned short* Kw = (unsigned short*)d_ws;
    unsigned short* Vw = Kw + (size_t)B_ * L_ * D_;
    prep_kv4<<<dim3(2 * B_ * NT), 256, 0, stream>>>(K, V, Kw, Vw);
    attn_fwd5<<<dim3(B_ * (L_ / QB)), 256, 0, stream>>>(Q, Kw, Vw, O);
  } else {
    attn_fwd_fb<<<dim3(B_ * (L_ / 64)), 256, 0, stream>>>(Q, K, V, O);
  }
}

// Round 6
// 191.054 us; speedup vs baseline: 1.7438x; 1.0125x over previous
//
#include <hip/hip_runtime.h>
#include <hip/hip_bf16.h>
#include <math.h>

typedef __attribute__((ext_vector_type(4))) float f32x4;
typedef __attribute__((ext_vector_type(8))) short s16x8;

#define B_    16
#define L_    4096
#define D_    64
#define QB    128          // q-rows per block (4 waves x 32)
#define KVB   64
#define NT    (L_ / KVB)

// 0.125 (1/sqrt(64)) * log2(e), folded into Q so softmax is pure exp2
#define QSCALE 0.18033688011112042f
#define THR    8.0f

__device__ __forceinline__ unsigned short f2bf(float x) {
  union { float f; unsigned u; } v; v.f = x;
  unsigned r = v.u + 0x7FFFu + ((v.u >> 16) & 1u);
  return (unsigned short)(r >> 16);
}

__device__ __forceinline__ int swz(int x) {
  return ((x & 7) ^ ((x >> 3) & 7)) << 4;
}

__device__ __forceinline__ void gload_lds16(const void* g, void* l) {
  __builtin_amdgcn_global_load_lds(
      (const __attribute__((address_space(1))) void*)g,
      (__attribute__((address_space(3))) void*)l, 16, 0, 0);
}

__device__ __forceinline__ unsigned cvtpk_bf16(float lo, float hi) {
  unsigned r;
  asm("v_cvt_pk_bf16_f32 %0, %1, %2" : "=v"(r) : "v"(lo), "v"(hi));
  return r;
}

__device__ __forceinline__ void pl32_swap(unsigned& a, unsigned& b) {
#if __has_builtin(__builtin_amdgcn_permlane32_swap)
  auto r = __builtin_amdgcn_permlane32_swap(a, b, false, false);
  a = r[0]; b = r[1];
#else
  asm volatile("v_permlane32_swap_b32 %0, %1" : "+v"(a), "+v"(b));
#endif
}

__device__ __forceinline__ void pl16_swap(unsigned& a, unsigned& b) {
#if __has_builtin(__builtin_amdgcn_permlane16_swap)
  auto r = __builtin_amdgcn_permlane16_swap(a, b, false, false);
  a = r[0]; b = r[1];
#else
  asm volatile("v_permlane16_swap_b32 %0, %1" : "+v"(a), "+v"(b));
#endif
}

__device__ __forceinline__ float fexp2(float x) {
#if __has_builtin(__builtin_amdgcn_exp2f)
  return __builtin_amdgcn_exp2f(x);
#else
  return exp2f(x);
#endif
}

// ---------------------------------------------------------------------------
// Prepass (unchanged from round 5).
// ---------------------------------------------------------------------------
__global__ __launch_bounds__(256) void prep_kv4(
    const float* __restrict__ Kg, const float* __restrict__ Vg,
    unsigned short* __restrict__ Kw, unsigned short* __restrict__ Vw) {
  __shared__ unsigned short vim[KVB * D_];
  const int tid = threadIdx.x;
  int blk = blockIdx.x;
  if (blk < B_ * NT) {
    const float* src = Kg + (size_t)blk * (KVB * D_);
    char* dst = (char*)(Kw + (size_t)blk * (KVB * D_));
#pragma unroll
    for (int c = 0; c < 2; ++c) {
      const int ch  = tid + c * 256;
      const int key = ch >> 3;
      const int seg = ch & 7;
      const float* p = src + key * D_ + seg * 8;
      f32x4 x0 = *(const f32x4*)p;
      f32x4 x1 = *(const f32x4*)(p + 4);
      union { s16x8 v; unsigned w[4]; } t_;
      t_.w[0] = cvtpk_bf16(x0[0], x0[1]);
      t_.w[1] = cvtpk_bf16(x0[2], x0[3]);
      t_.w[2] = cvtpk_bf16(x1[0], x1[1]);
      t_.w[3] = cvtpk_bf16(x1[2], x1[3]);
      *(s16x8*)(dst + ((key * 128 + seg * 16) ^ swz(key))) = t_.v;
    }
  } else {
    blk -= B_ * NT;
    const int skey2 = (tid >> 3) * 2;
    const int sdseg = tid & 7;
    const float* vp0 = Vg + ((size_t)blk * KVB + skey2) * D_ + sdseg * 8;
    char* vimc = (char*)vim;
    f32x4 v0 = *(const f32x4*)(vp0);
    f32x4 v1 = *(const f32x4*)(vp0 + 4);
    f32x4 v2 = *(const f32x4*)(vp0 + D_);
    f32x4 v3 = *(const f32x4*)(vp0 + D_ + 4);
#pragma unroll
    for (int u = 0; u < 2; ++u) {
#pragma unroll
      for (int i = 0; i < 4; ++i) {
        const int d = sdseg * 8 + u * 4 + i;
        unsigned pk = cvtpk_bf16(u ? v1[i] : v0[i], u ? v3[i] : v2[i]);
        *(unsigned*)(vimc + ((d * 128 + skey2 * 2) ^ swz(d))) = pk;
      }
    }
    __syncthreads();
    char* vout = (char*)(Vw + (size_t)blk * (KVB * D_));
#pragma unroll
    for (int c = 0; c < 2; ++c) {
      const int off = c * 4096 + tid * 16;
      *(s16x8*)(vout + off) = *(const s16x8*)(vimc + off);
    }
  }
}

// ---------------------------------------------------------------------------
// Main kernel: counted-vmcnt 4-buffer pipeline (loads never drained to 0
// inside the loop), raw s_barrier, 32 q-rows/wave sharing, in-register P.
// ---------------------------------------------------------------------------
__global__ __launch_bounds__(256, 2) void attn_fwd6(
    const float* __restrict__ Qg, const unsigned short* __restrict__ Kw,
    const unsigned short* __restrict__ Vw, float* __restrict__ Og) {
  __shared__ unsigned short Ks[4][KVB * D_];   // 4 x 8KB
  __shared__ unsigned short Vs[4][KVB * D_];   // 4 x 8KB

  const int tid  = threadIdx.x;
  const int wv   = tid >> 6;
  const int lane = tid & 63;
  const int rl   = lane & 15;   // q-row within half
  const int kb   = lane >> 4;
  const int kb4  = kb * 4;

  const int blk = blockIdx.x;
  const int b   = blk >> 5;      // L_/QB = 32
  const int qt  = blk & 31;

  // ---- Q B-frags for both halves, QSCALE folded ----
  const float* qbase = Qg + ((size_t)b * L_ + qt * QB + wv * 32) * D_;
  s16x8 aq0[2], aq1[2];
#pragma unroll
  for (int qh = 0; qh < 2; ++qh) {
    const float* qrow_p = qbase + (qh * 16 + rl) * D_;
#pragma unroll
    for (int h = 0; h < 2; ++h) {
      const float* p = qrow_p + h * 32 + kb * 8;
      f32x4 x0 = *(const f32x4*)p;
      f32x4 x1 = *(const f32x4*)(p + 4);
      union { s16x8 v; unsigned w[4]; } t_;
      t_.w[0] = cvtpk_bf16(x0[0] * QSCALE, x0[1] * QSCALE);
      t_.w[1] = cvtpk_bf16(x0[2] * QSCALE, x0[3] * QSCALE);
      t_.w[2] = cvtpk_bf16(x1[0] * QSCALE, x1[1] * QSCALE);
      t_.w[3] = cvtpk_bf16(x1[2] * QSCALE, x1[3] * QSCALE);
      if (qh == 0) aq0[h] = t_.v; else aq1[h] = t_.v;
    }
  }

  // ---- loop-invariant LDS read offsets (same formula for K and V) ----
  int offA[4], offB[4];
#pragma unroll
  for (int t = 0; t < 4; ++t) {
    const int row  = t * 16 + rl;
    const int base = row * 128 + kb * 16;
    offA[t] = base ^ swz(row);
    offB[t] = (base + 64) ^ swz(row);
  }

  f32x4 oacc0[4], oacc1[4];
#pragma unroll
  for (int t = 0; t < 4; ++t) {
    oacc0[t] = (f32x4){0.f, 0.f, 0.f, 0.f};
    oacc1[t] = (f32x4){0.f, 0.f, 0.f, 0.f};
  }
  float m0 = -3.0e38f, m1 = -3.0e38f, l0 = 0.f, l1 = 0.f;

  char* ks0 = (char*)(&Ks[0][0]);
  char* vs0 = (char*)(&Vs[0][0]);
  const int woff = wv * 2048;
  const char* kt = (const char*)(Kw + (size_t)b * L_ * D_) + woff + lane * 16;
  const char* vt = (const char*)(Vw + (size_t)b * L_ * D_) + woff + lane * 16;

  auto issue = [&](int bi) {
    char* kd = ks0 + bi * 8192 + woff;
    char* vd = vs0 + bi * 8192 + woff;
    gload_lds16(kt,        kd);
    gload_lds16(kt + 1024, kd + 1024);
    gload_lds16(vt,        vd);
    gload_lds16(vt + 1024, vd + 1024);
    kt += 8192; vt += 8192;
  };

  auto compute = [&](const char* kbase, const char* vbase) {
    // ---- S' = K Q^T for both q-halves; K frags read once ----
    f32x4 s0[4], s1[4];
    __builtin_amdgcn_s_setprio(1);
#pragma unroll
    for (int t = 0; t < 4; ++t) {
      s16x8 k0 = *(const s16x8*)(kbase + offA[t]);
      s16x8 k1 = *(const s16x8*)(kbase + offB[t]);
      f32x4 a = (f32x4){0.f, 0.f, 0.f, 0.f};
      f32x4 c = (f32x4){0.f, 0.f, 0.f, 0.f};
      a = __builtin_amdgcn_mfma_f32_16x16x32_bf16(k0, aq0[0], a, 0, 0, 0);
      c = __builtin_amdgcn_mfma_f32_16x16x32_bf16(k0, aq1[0], c, 0, 0, 0);
      a = __builtin_amdgcn_mfma_f32_16x16x32_bf16(k1, aq0[1], a, 0, 0, 0);
      c = __builtin_amdgcn_mfma_f32_16x16x32_bf16(k1, aq1[1], c, 0, 0, 0);
      s0[t] = a; s1[t] = c;
    }
    __builtin_amdgcn_s_setprio(0);

    // ---- lane-local maxima ----
    float x0 = fmaxf(fmaxf(s0[0][0], s0[0][1]), fmaxf(s0[0][2], s0[0][3]));
    float x1 = fmaxf(fmaxf(s0[1][0], s0[1][1]), fmaxf(s0[1][2], s0[1][3]));
    float x2 = fmaxf(fmaxf(s0[2][0], s0[2][1]), fmaxf(s0[2][2], s0[2][3]));
    float x3 = fmaxf(fmaxf(s0[3][0], s0[3][1]), fmaxf(s0[3][2], s0[3][3]));
    float mx0 = fmaxf(fmaxf(x0, x1), fmaxf(x2, x3));
    float y0 = fmaxf(fmaxf(s1[0][0], s1[0][1]), fmaxf(s1[0][2], s1[0][3]));
    float y1 = fmaxf(fmaxf(s1[1][0], s1[1][1]), fmaxf(s1[1][2], s1[1][3]));
    float y2 = fmaxf(fmaxf(s1[2][0], s1[2][1]), fmaxf(s1[2][2], s1[2][3]));
    float y3 = fmaxf(fmaxf(s1[3][0], s1[3][1]), fmaxf(s1[3][2], s1[3][3]));
    float mx1 = fmaxf(fmaxf(y0, y1), fmaxf(y2, y3));

    // ---- defer-max rescale (rare) ----
    if (__any((mx0 > m0 + THR) || (mx1 > m1 + THR))) {
      float r0 = fmaxf(mx0, __shfl_xor(mx0, 16));
      r0 = fmaxf(r0, __shfl_xor(r0, 32));
      float r1 = fmaxf(mx1, __shfl_xor(mx1, 16));
      r1 = fmaxf(r1, __shfl_xor(r1, 32));
      const float n0 = fmaxf(m0, r0);
      const float n1 = fmaxf(m1, r1);
      const float al0 = fexp2(m0 - n0);
      const float al1 = fexp2(m1 - n1);
      m0 = n0; m1 = n1;
      l0 *= al0; l1 *= al1;
#pragma unroll
      for (int j = 0; j < 4; ++j) {
        const float b0 = __shfl(al0, kb4 + j);
        const float b1 = __shfl(al1, kb4 + j);
#pragma unroll
        for (int t = 0; t < 4; ++t) {
          oacc0[t][j] *= b0;
          oacc1[t][j] *= b1;
        }
      }
    }

    // ---- P = exp2(S - m) fused with bf16 pack ----
    unsigned W0[4][2], W1[4][2];
    float rs0 = 0.f, rs1 = 0.f;
#pragma unroll
    for (int t = 0; t < 4; ++t) {
      const float e0 = fexp2(s0[t][0] - m0);
      const float e1 = fexp2(s0[t][1] - m0);
      const float e2 = fexp2(s0[t][2] - m0);
      const float e3 = fexp2(s0[t][3] - m0);
      rs0 += (e0 + e1) + (e2 + e3);
      W0[t][0] = cvtpk_bf16(e0, e1);
      W0[t][1] = cvtpk_bf16(e2, e3);
      const float f0 = fexp2(s1[t][0] - m1);
      const float f1 = fexp2(s1[t][1] - m1);
      const float f2 = fexp2(s1[t][2] - m1);
      const float f3 = fexp2(s1[t][3] - m1);
      rs1 += (f0 + f1) + (f2 + f3);
      W1[t][0] = cvtpk_bf16(f0, f1);
      W1[t][1] = cvtpk_bf16(f2, f3);
    }
    l0 += rs0; l1 += rs1;

    // ---- permute P into PV A-fragments ----
    union { s16x8 v; unsigned w[4]; } A00, A01, A10, A11;
#pragma unroll
    for (int u = 0; u < 2; ++u) {
      { unsigned x = W0[0][u], y = W0[1][u];
        pl32_swap(x, y); pl16_swap(x, y);
        A00.w[u] = x; A00.w[u + 2] = y; }
      { unsigned x = W0[2][u], y = W0[3][u];
        pl32_swap(x, y); pl16_swap(x, y);
        A01.w[u] = x; A01.w[u + 2] = y; }
      { unsigned x = W1[0][u], y = W1[1][u];
        pl32_swap(x, y); pl16_swap(x, y);
        A10.w[u] = x; A10.w[u + 2] = y; }
      { unsigned x = W1[2][u], y = W1[3][u];
        pl32_swap(x, y); pl16_swap(x, y);
        A11.w[u] = x; A11.w[u + 2] = y; }
    }

    // ---- O += P V; V frags read once, used by both halves ----
    __builtin_amdgcn_s_setprio(1);
#pragma unroll
    for (int t = 0; t < 4; ++t) {
      s16x8 bv0 = *(const s16x8*)(vbase + offA[t]);
      s16x8 bv1 = *(const s16x8*)(vbase + offB[t]);
      f32x4 a = oacc0[t];
      f32x4 c = oacc1[t];
      a = __builtin_amdgcn_mfma_f32_16x16x32_bf16(A00.v, bv0, a, 0, 0, 0);
      c = __builtin_amdgcn_mfma_f32_16x16x32_bf16(A10.v, bv0, c, 0, 0, 0);
      a = __builtin_amdgcn_mfma_f32_16x16x32_bf16(A01.v, bv1, a, 0, 0, 0);
      c = __builtin_amdgcn_mfma_f32_16x16x32_bf16(A11.v, bv1, c, 0, 0, 0);
      oacc0[t] = a; oacc1[t] = c;
    }
    __builtin_amdgcn_s_setprio(0);
  };

  // ---- prologue: issue tiles 0,1,2 (depth-3 pipeline) ----
  issue(0); issue(1); issue(2);

  // ---- main loop: one barrier per tile, vmcnt floor = 8 (2 tiles in flight)
  for (int i = 0; i < NT - 3; ++i) {
    asm volatile("s_waitcnt vmcnt(8)" ::: "memory");  // tile i landed
    __builtin_amdgcn_sched_barrier(0);
    __builtin_amdgcn_s_barrier();                     // all waves: tile i ready
    __builtin_amdgcn_sched_barrier(0);
    issue((i + 3) & 3);   // overwrites buf of tile i-1 (all waves past it)
    compute(ks0 + (i & 3) * 8192, vs0 + (i & 3) * 8192);
  }

  // ---- tail: tiles NT-3, NT-2, NT-1 (no more issues) ----
  asm volatile("s_waitcnt vmcnt(8)" ::: "memory");
  __builtin_amdgcn_sched_barrier(0);
  __builtin_amdgcn_s_barrier();
  __builtin_amdgcn_sched_barrier(0);
  compute(ks0 + ((NT - 3) & 3) * 8192, vs0 + ((NT - 3) & 3) * 8192);

  asm volatile("s_waitcnt vmcnt(4)" ::: "memory");
  __builtin_amdgcn_sched_barrier(0);
  __builtin_amdgcn_s_barrier();
  __builtin_amdgcn_sched_barrier(0);
  compute(ks0 + ((NT - 2) & 3) * 8192, vs0 + ((NT - 2) & 3) * 8192);

  asm volatile("s_waitcnt vmcnt(0)" ::: "memory");
  __builtin_amdgcn_sched_barrier(0);
  __builtin_amdgcn_s_barrier();
  __builtin_amdgcn_sched_barrier(0);
  compute(ks0 + ((NT - 1) & 3) * 8192, vs0 + ((NT - 1) & 3) * 8192);

  // ---- epilogue: per-half row sums, normalize, store ----
  float t0 = l0 + __shfl_xor(l0, 16);
  t0 += __shfl_xor(t0, 32);
  float t1 = l1 + __shfl_xor(l1, 16);
  t1 += __shfl_xor(t1, 32);
  const float v0i = 1.0f / t0;
  const float v1i = 1.0f / t1;

  float* ob = Og + ((size_t)b * L_ + qt * QB + wv * 32 + kb4) * D_;
#pragma unroll
  for (int j = 0; j < 4; ++j) {
    const float i0 = __shfl(v0i, kb4 + j);
    const float i1 = __shfl(v1i, kb4 + j);
    float* r0 = ob + (size_t)j * D_;
    float* r1 = r0 + 16 * D_;
#pragma unroll
    for (int t = 0; t < 4; ++t) {
      r0[t * 16 + rl] = oacc0[t][j] * i0;
      r1[t * 16 + rl] = oacc1[t][j] * i1;
    }
  }
}

// ---------------------------------------------------------------------------
// Fallback (no-workspace path).
// ---------------------------------------------------------------------------
__global__ __launch_bounds__(256) void attn_fwd_fb(
    const float* __restrict__ Qg, const float* __restrict__ Kg,
    const float* __restrict__ Vg, float* __restrict__ Og) {
  __shared__ unsigned short Ksf[KVB * D_];
  __shared__ unsigned short Vsf[KVB * D_];
  __shared__ unsigned short Psf[4][16 * KVB];

  const int tid  = threadIdx.x;
  const int wv   = tid >> 6;
  const int lane = tid & 63;
  const int rl   = lane & 15;
  const int kb   = lane >> 4;

  const int blk = blockIdx.x;
  const int b   = blk / (L_ / 64);
  const int qt  = blk % (L_ / 64);

  const float* qrow_p = Qg + ((size_t)b * L_ + qt * 64 + wv * 16 + rl) * D_;
  s16x8 aq[2];
#pragma unroll
  for (int h = 0; h < 2; ++h) {
    const float* p = qrow_p + h * 32 + kb * 8;
    f32x4 x0 = *(const f32x4*)p;
    f32x4 x1 = *(const f32x4*)(p + 4);
    s16x8 w;
#pragma unroll
    for (int i = 0; i < 4; ++i) {
      w[i]     = (short)f2bf(x0[i] * QSCALE);
      w[i + 4] = (short)f2bf(x1[i] * QSCALE);
    }
    aq[h] = w;
  }

  f32x4 oacc[4];
  float m_r[4], l_r[4];
#pragma unroll
  for (int t = 0; t < 4; ++t) oacc[t] = (f32x4){0.f, 0.f, 0.f, 0.f};
#pragma unroll
  for (int j = 0; j < 4; ++j) { m_r[j] = -3.0e38f; l_r[j] = 0.f; }

  const float* kb_p = Kg + (size_t)b * L_ * D_;
  const float* vb_p = Vg + (size_t)b * L_ * D_;
  const int skey2 = (tid >> 3) * 2;
  const int sdseg = tid & 7;

  char* ksc = (char*)Ksf;
  char* vsc = (char*)Vsf;
  char* psc = (char*)(Psf[wv]);

  for (int kv = 0; kv < L_; kv += KVB) {
    __syncthreads();
    {
      const float* kp0 = kb_p + (size_t)(kv + skey2) * D_ + sdseg * 8;
      const float* vp0 = vb_p + (size_t)(kv + skey2) * D_ + sdseg * 8;
#pragma unroll
      for (int q2 = 0; q2 < 2; ++q2) {
        const int key = skey2 + q2;
        f32x4 a0 = *(const f32x4*)(kp0 + q2 * D_);
        f32x4 a1 = *(const f32x4*)(kp0 + q2 * D_ + 4);
        s16x8 w;
#pragma unroll
        for (int i = 0; i < 4; ++i) {
          w[i]     = (short)f2bf(a0[i]);
          w[i + 4] = (short)f2bf(a1[i]);
        }
        *(s16x8*)(ksc + ((key * 128 + sdseg * 16) ^ swz(key))) = w;
      }
      f32x4 v0 = *(const f32x4*)(vp0);
      f32x4 v1 = *(const f32x4*)(vp0 + 4);
      f32x4 v2 = *(const f32x4*)(vp0 + D_);
      f32x4 v3 = *(const f32x4*)(vp0 + D_ + 4);
#pragma unroll
      for (int u = 0; u < 2; ++u) {
#pragma unroll
        for (int i = 0; i < 4; ++i) {
          const int d = sdseg * 8 + u * 4 + i;
          unsigned lo = (unsigned)f2bf(u ? v1[i] : v0[i]);
          unsigned hi = (unsigned)f2bf(u ? v3[i] : v2[i]);
          *(unsigned*)(vsc + ((d * 128 + skey2 * 2) ^ swz(d))) = lo | (hi << 16);
        }
      }
    }
    __syncthreads();

    f32x4 s[4];
#pragma unroll
    for (int t = 0; t < 4; ++t) {
      const int key  = t * 16 + rl;
      const int base = key * 128 + kb * 16;
      s16x8 b0 = *(const s16x8*)(ksc + ((base)      ^ swz(key)));
      s16x8 b1 = *(const s16x8*)(ksc + ((base + 64) ^ swz(key)));
      f32x4 acc = (f32x4){0.f, 0.f, 0.f, 0.f};
      acc = __builtin_amdgcn_mfma_f32_16x16x32_bf16(aq[0], b0, acc, 0, 0, 0);
      acc = __builtin_amdgcn_mfma_f32_16x16x32_bf16(aq[1], b1, acc, 0, 0, 0);
      s[t] = acc;
    }

    float alpha[4];
#pragma unroll
    for (int j = 0; j < 4; ++j) {
      float mx = fmaxf(fmaxf(s[0][j], s[1][j]), fmaxf(s[2][j], s[3][j]));
      mx = fmaxf(mx, __shfl_xor(mx, 1));
      mx = fmaxf(mx, __shfl_xor(mx, 2));
      mx = fmaxf(mx, __shfl_xor(mx, 4));
      mx = fmaxf(mx, __shfl_xor(mx, 8));
      const float mn = fmaxf(m_r[j], mx);
      alpha[j] = fexp2(m_r[j] - mn);
      m_r[j]   = mn;
    }

    float rs[4] = {0.f, 0.f, 0.f, 0.f};
#pragma unroll
    for (int t = 0; t < 4; ++t)
#pragma unroll
      for (int j = 0; j < 4; ++j) {
        const float p = fexp2(s[t][j] - m_r[j]);
        rs[j] += p;
        const int row = kb * 4 + j;
        *(unsigned short*)(psc + ((row * 128 + (t * 16 + rl) * 2) ^ swz(row))) = f2bf(p);
      }
#pragma unroll
    for (int j = 0; j < 4; ++j) l_r[j] = l_r[j] * alpha[j] + rs[j];

#pragma unroll
    for (int t = 0; t < 4; ++t)
#pragma unroll
      for (int j = 0; j < 4; ++j) oacc[t][j] *= alpha[j];

    s16x8 ap[2];
#pragma unroll
    for (int h = 0; h < 2; ++h) {
      const int base = rl * 128 + h * 64 + kb * 16;
      ap[h] = *(const s16x8*)(psc + (base ^ swz(rl)));
    }
#pragma unroll
    for (int t = 0; t < 4; ++t) {
      const int d    = t * 16 + rl;
      const int base = d * 128 + kb * 16;
      s16x8 bv0 = *(const s16x8*)(vsc + ((base)      ^ swz(d)));
      s16x8 bv1 = *(const s16x8*)(vsc + ((base + 64) ^ swz(d)));
      f32x4 acc = oacc[t];
      acc = __builtin_amdgcn_mfma_f32_16x16x32_bf16(ap[0], bv0, acc, 0, 0, 0);
      acc = __builtin_amdgcn_mfma_f32_16x16x32_bf16(ap[1], bv1, acc, 0, 0, 0);
      oacc[t] = acc;
    }
  }

  float inv[4];
#pragma unroll
  for (int j = 0; j < 4; ++j) {
    float r = l_r[j];
    r += __shfl_xor(r, 1);
    r += __shfl_xor(r, 2);
    r += __shfl_xor(r, 4);
    r += __shfl_xor(r, 8);
    inv[j] = 1.0f / r;
  }
  float* op = Og + ((size_t)b * L_ + qt * 64 + wv * 16 + kb * 4) * D_;
#pragma unroll
  for (int j = 0; j < 4; ++j)
#pragma unroll
    for (int t = 0; t < 4; ++t)
      op[(size_t)j * D_ + t * 16 + rl] = oacc[t][j] * inv[j];
}

extern "C" void kernel_launch(void* const* d_in, const int* in_sizes, int n_in,
                              void* d_out, int out_size, void* d_ws, size_t ws_size,
                              hipStream_t stream) {
  (void)in_sizes; (void)n_in; (void)out_size;
  const float* Q = (const float*)d_in[0];
  const float* K = (const float*)d_in[1];
  const float* V = (const float*)d_in[2];
  float* O = (float*)d_out;

  const size_t need = (size_t)2 * B_ * L_ * D_ * sizeof(unsigned short);  // 16 MB
  if (d_ws != nullptr && ws_size >= need) {
    unsigned short* Kw = (unsigned short*)d_ws;
    unsigned short* Vw = Kw + (size_t)B_ * L_ * D_;
    prep_kv4<<<dim3(2 * B_ * NT), 256, 0, stream>>>(K, V, Kw, Vw);
    attn_fwd6<<<dim3(B_ * (L_ / QB)), 256, 0, stream>>>(Q, Kw, Vw, O);
  } else {
    attn_fwd_fb<<<dim3(B_ * (L_ / 64)), 256, 0, stream>>>(Q, K, V, O);
  }
}

// Round 9
// 189.224 us; speedup vs baseline: 1.7606x; 1.0097x over previous
//
#include <hip/hip_runtime.h>
#include <hip/hip_bf16.h>
#include <math.h>

typedef __attribute__((ext_vector_type(4))) float f32x4;
typedef __attribute__((ext_vector_type(8))) short s16x8;

#define B_    16
#define L_    4096
#define D_    64
#define QB    128          // q-rows per block (4 waves x 32)
#define KVB   64
#define NT    (L_ / KVB)   // 64 sub-tiles

// 0.125 (1/sqrt(64)) * log2(e), folded into Q so softmax is pure exp2
#define QSCALE 0.18033688011112042f
#define THR    8.0f

__device__ __forceinline__ unsigned short f2bf(float x) {
  union { float f; unsigned u; } v; v.f = x;
  unsigned r = v.u + 0x7FFFu + ((v.u >> 16) & 1u);
  return (unsigned short)(r >> 16);
}

__device__ __forceinline__ int swz(int x) {
  return ((x & 7) ^ ((x >> 3) & 7)) << 4;
}

__device__ __forceinline__ void gload_lds16(const void* g, void* l) {
  __builtin_amdgcn_global_load_lds(
      (const __attribute__((address_space(1))) void*)g,
      (__attribute__((address_space(3))) void*)l, 16, 0, 0);
}

__device__ __forceinline__ unsigned cvtpk_bf16(float lo, float hi) {
  unsigned r;
  asm("v_cvt_pk_bf16_f32 %0, %1, %2" : "=v"(r) : "v"(lo), "v"(hi));
  return r;
}

__device__ __forceinline__ void pl32_swap(unsigned& a, unsigned& b) {
#if __has_builtin(__builtin_amdgcn_permlane32_swap)
  auto r = __builtin_amdgcn_permlane32_swap(a, b, false, false);
  a = r[0]; b = r[1];
#else
  asm volatile("v_permlane32_swap_b32 %0, %1" : "+v"(a), "+v"(b));
#endif
}

__device__ __forceinline__ void pl16_swap(unsigned& a, unsigned& b) {
#if __has_builtin(__builtin_amdgcn_permlane16_swap)
  auto r = __builtin_amdgcn_permlane16_swap(a, b, false, false);
  a = r[0]; b = r[1];
#else
  asm volatile("v_permlane16_swap_b32 %0, %1" : "+v"(a), "+v"(b));
#endif
}

__device__ __forceinline__ float fexp2(float x) {
#if __has_builtin(__builtin_amdgcn_exp2f)
  return __builtin_amdgcn_exp2f(x);
#else
  return exp2f(x);
#endif
}

// ---------------------------------------------------------------------------
// Prepass (unchanged).
// ---------------------------------------------------------------------------
__global__ __launch_bounds__(256) void prep_kv4(
    const float* __restrict__ Kg, const float* __restrict__ Vg,
    unsigned short* __restrict__ Kw, unsigned short* __restrict__ Vw) {
  __shared__ unsigned short vim[KVB * D_];
  const int tid = threadIdx.x;
  int blk = blockIdx.x;
  if (blk < B_ * NT) {
    const float* src = Kg + (size_t)blk * (KVB * D_);
    char* dst = (char*)(Kw + (size_t)blk * (KVB * D_));
#pragma unroll
    for (int c = 0; c < 2; ++c) {
      const int ch  = tid + c * 256;
      const int key = ch >> 3;
      const int seg = ch & 7;
      const float* p = src + key * D_ + seg * 8;
      f32x4 x0 = *(const f32x4*)p;
      f32x4 x1 = *(const f32x4*)(p + 4);
      union { s16x8 v; unsigned w[4]; } t_;
      t_.w[0] = cvtpk_bf16(x0[0], x0[1]);
      t_.w[1] = cvtpk_bf16(x0[2], x0[3]);
      t_.w[2] = cvtpk_bf16(x1[0], x1[1]);
      t_.w[3] = cvtpk_bf16(x1[2], x1[3]);
      *(s16x8*)(dst + ((key * 128 + seg * 16) ^ swz(key))) = t_.v;
    }
  } else {
    blk -= B_ * NT;
    const int skey2 = (tid >> 3) * 2;
    const int sdseg = tid & 7;
    const float* vp0 = Vg + ((size_t)blk * KVB + skey2) * D_ + sdseg * 8;
    char* vimc = (char*)vim;
    f32x4 v0 = *(const f32x4*)(vp0);
    f32x4 v1 = *(const f32x4*)(vp0 + 4);
    f32x4 v2 = *(const f32x4*)(vp0 + D_);
    f32x4 v3 = *(const f32x4*)(vp0 + D_ + 4);
#pragma unroll
    for (int u = 0; u < 2; ++u) {
#pragma unroll
      for (int i = 0; i < 4; ++i) {
        const int d = sdseg * 8 + u * 4 + i;
        unsigned pk = cvtpk_bf16(u ? v1[i] : v0[i], u ? v3[i] : v2[i]);
        *(unsigned*)(vimc + ((d * 128 + skey2 * 2) ^ swz(d))) = pk;
      }
    }
    __syncthreads();
    char* vout = (char*)(Vw + (size_t)blk * (KVB * D_));
#pragma unroll
    for (int c = 0; c < 2; ++c) {
      const int off = c * 4096 + tid * 16;
      *(s16x8*)(vout + off) = *(const s16x8*)(vimc + off);
    }
  }
}

// ---------------------------------------------------------------------------
// Main kernel: pair-window pipeline — 5 LDS buffers, one barrier + one
// counted vmcnt per TWO sub-tiles; two independent softmax chains per
// scheduling window.
// ---------------------------------------------------------------------------
__global__ __launch_bounds__(256, 2) void attn_fwd7(
    const float* __restrict__ Qg, const unsigned short* __restrict__ Kw,
    const unsigned short* __restrict__ Vw, float* __restrict__ Og) {
  __shared__ unsigned short Ks[5][KVB * D_];   // 5 x 8KB
  __shared__ unsigned short Vs[5][KVB * D_];   // 5 x 8KB

  const int tid  = threadIdx.x;
  const int wv   = tid >> 6;
  const int lane = tid & 63;
  const int rl   = lane & 15;   // q-row within half
  const int kb   = lane >> 4;
  const int kb4  = kb * 4;

  const int blk = blockIdx.x;
  const int b   = blk >> 5;      // L_/QB = 32
  const int qt  = blk & 31;

  // ---- Q B-frags for both halves, QSCALE folded ----
  const float* qbase = Qg + ((size_t)b * L_ + qt * QB + wv * 32) * D_;
  s16x8 aq0[2], aq1[2];
#pragma unroll
  for (int qh = 0; qh < 2; ++qh) {
    const float* qrow_p = qbase + (qh * 16 + rl) * D_;
#pragma unroll
    for (int h = 0; h < 2; ++h) {
      const float* p = qrow_p + h * 32 + kb * 8;
      f32x4 x0 = *(const f32x4*)p;
      f32x4 x1 = *(const f32x4*)(p + 4);
      union { s16x8 v; unsigned w[4]; } t_;
      t_.w[0] = cvtpk_bf16(x0[0] * QSCALE, x0[1] * QSCALE);
      t_.w[1] = cvtpk_bf16(x0[2] * QSCALE, x0[3] * QSCALE);
      t_.w[2] = cvtpk_bf16(x1[0] * QSCALE, x1[1] * QSCALE);
      t_.w[3] = cvtpk_bf16(x1[2] * QSCALE, x1[3] * QSCALE);
      if (qh == 0) aq0[h] = t_.v; else aq1[h] = t_.v;
    }
  }

  // ---- loop-invariant LDS read offsets (same formula for K and V) ----
  int offA[4], offB[4];
#pragma unroll
  for (int t = 0; t < 4; ++t) {
    const int row  = t * 16 + rl;
    const int base = row * 128 + kb * 16;
    offA[t] = base ^ swz(row);
    offB[t] = (base + 64) ^ swz(row);
  }

  f32x4 oacc0[4], oacc1[4];
#pragma unroll
  for (int t = 0; t < 4; ++t) {
    oacc0[t] = (f32x4){0.f, 0.f, 0.f, 0.f};
    oacc1[t] = (f32x4){0.f, 0.f, 0.f, 0.f};
  }
  float m0 = -3.0e38f, m1 = -3.0e38f, l0 = 0.f, l1 = 0.f;

  char* ks0 = (char*)(&Ks[0][0]);
  char* vs0 = (char*)(&Vs[0][0]);
  const int woff   = wv * 2048;
  const int lane16 = lane * 16;
  const char* kimg = (const char*)(Kw + (size_t)b * L_ * D_) + woff + lane16;
  const char* vimg = (const char*)(Vw + (size_t)b * L_ * D_) + woff + lane16;

  auto issue = [&](int s, int bi) {
    const char* kg = kimg + (size_t)s * 8192;
    const char* vg = vimg + (size_t)s * 8192;
    char* kd = ks0 + bi * 8192 + woff;
    char* vd = vs0 + bi * 8192 + woff;
    gload_lds16(kg,        kd);
    gload_lds16(kg + 1024, kd + 1024);
    gload_lds16(vg,        vd);
    gload_lds16(vg + 1024, vd + 1024);
  };

  auto compute = [&](const char* kbase, const char* vbase) {
    // ---- S' = K Q^T for both q-halves; K frags read once ----
    f32x4 s0[4], s1[4];
#pragma unroll
    for (int t = 0; t < 4; ++t) {
      s16x8 k0 = *(const s16x8*)(kbase + offA[t]);
      s16x8 k1 = *(const s16x8*)(kbase + offB[t]);
      f32x4 a = (f32x4){0.f, 0.f, 0.f, 0.f};
      f32x4 c = (f32x4){0.f, 0.f, 0.f, 0.f};
      a = __builtin_amdgcn_mfma_f32_16x16x32_bf16(k0, aq0[0], a, 0, 0, 0);
      c = __builtin_amdgcn_mfma_f32_16x16x32_bf16(k0, aq1[0], c, 0, 0, 0);
      a = __builtin_amdgcn_mfma_f32_16x16x32_bf16(k1, aq0[1], a, 0, 0, 0);
      c = __builtin_amdgcn_mfma_f32_16x16x32_bf16(k1, aq1[1], c, 0, 0, 0);
      s0[t] = a; s1[t] = c;
    }

    // ---- lane-local maxima ----
    float x0 = fmaxf(fmaxf(s0[0][0], s0[0][1]), fmaxf(s0[0][2], s0[0][3]));
    float x1 = fmaxf(fmaxf(s0[1][0], s0[1][1]), fmaxf(s0[1][2], s0[1][3]));
    float x2 = fmaxf(fmaxf(s0[2][0], s0[2][1]), fmaxf(s0[2][2], s0[2][3]));
    float x3 = fmaxf(fmaxf(s0[3][0], s0[3][1]), fmaxf(s0[3][2], s0[3][3]));
    float mx0 = fmaxf(fmaxf(x0, x1), fmaxf(x2, x3));
    float y0 = fmaxf(fmaxf(s1[0][0], s1[0][1]), fmaxf(s1[0][2], s1[0][3]));
    float y1 = fmaxf(fmaxf(s1[1][0], s1[1][1]), fmaxf(s1[1][2], s1[1][3]));
    float y2 = fmaxf(fmaxf(s1[2][0], s1[2][1]), fmaxf(s1[2][2], s1[2][3]));
    float y3 = fmaxf(fmaxf(s1[3][0], s1[3][1]), fmaxf(s1[3][2], s1[3][3]));
    float mx1 = fmaxf(fmaxf(y0, y1), fmaxf(y2, y3));

    // ---- defer-max rescale (rare) ----
    if (__any((mx0 > m0 + THR) || (mx1 > m1 + THR))) {
      float r0 = fmaxf(mx0, __shfl_xor(mx0, 16));
      r0 = fmaxf(r0, __shfl_xor(r0, 32));
      float r1 = fmaxf(mx1, __shfl_xor(mx1, 16));
      r1 = fmaxf(r1, __shfl_xor(r1, 32));
      const float n0 = fmaxf(m0, r0);
      const float n1 = fmaxf(m1, r1);
      const float al0 = fexp2(m0 - n0);
      const float al1 = fexp2(m1 - n1);
      m0 = n0; m1 = n1;
      l0 *= al0; l1 *= al1;
#pragma unroll
      for (int j = 0; j < 4; ++j) {
        const float b0 = __shfl(al0, kb4 + j);
        const float b1 = __shfl(al1, kb4 + j);
#pragma unroll
        for (int t = 0; t < 4; ++t) {
          oacc0[t][j] *= b0;
          oacc1[t][j] *= b1;
        }
      }
    }

    // ---- P = exp2(S - m) fused with bf16 pack ----
    unsigned W0[4][2], W1[4][2];
    float rs0 = 0.f, rs1 = 0.f;
#pragma unroll
    for (int t = 0; t < 4; ++t) {
      const float e0 = fexp2(s0[t][0] - m0);
      const float e1 = fexp2(s0[t][1] - m0);
      const float e2 = fexp2(s0[t][2] - m0);
      const float e3 = fexp2(s0[t][3] - m0);
      rs0 += (e0 + e1) + (e2 + e3);
      W0[t][0] = cvtpk_bf16(e0, e1);
      W0[t][1] = cvtpk_bf16(e2, e3);
      const float f0 = fexp2(s1[t][0] - m1);
      const float f1 = fexp2(s1[t][1] - m1);
      const float f2 = fexp2(s1[t][2] - m1);
      const float f3 = fexp2(s1[t][3] - m1);
      rs1 += (f0 + f1) + (f2 + f3);
      W1[t][0] = cvtpk_bf16(f0, f1);
      W1[t][1] = cvtpk_bf16(f2, f3);
    }
    l0 += rs0; l1 += rs1;

    // ---- permute P into PV A-fragments ----
    union { s16x8 v; unsigned w[4]; } A00, A01, A10, A11;
#pragma unroll
    for (int u = 0; u < 2; ++u) {
      { unsigned x = W0[0][u], y = W0[1][u];
        pl32_swap(x, y); pl16_swap(x, y);
        A00.w[u] = x; A00.w[u + 2] = y; }
      { unsigned x = W0[2][u], y = W0[3][u];
        pl32_swap(x, y); pl16_swap(x, y);
        A01.w[u] = x; A01.w[u + 2] = y; }
      { unsigned x = W1[0][u], y = W1[1][u];
        pl32_swap(x, y); pl16_swap(x, y);
        A10.w[u] = x; A10.w[u + 2] = y; }
      { unsigned x = W1[2][u], y = W1[3][u];
        pl32_swap(x, y); pl16_swap(x, y);
        A11.w[u] = x; A11.w[u + 2] = y; }
    }

    // ---- O += P V; V frags read once, used by both halves ----
#pragma unroll
    for (int t = 0; t < 4; ++t) {
      s16x8 bv0 = *(const s16x8*)(vbase + offA[t]);
      s16x8 bv1 = *(const s16x8*)(vbase + offB[t]);
      f32x4 a = oacc0[t];
      f32x4 c = oacc1[t];
      a = __builtin_amdgcn_mfma_f32_16x16x32_bf16(A00.v, bv0, a, 0, 0, 0);
      c = __builtin_amdgcn_mfma_f32_16x16x32_bf16(A10.v, bv0, c, 0, 0, 0);
      a = __builtin_amdgcn_mfma_f32_16x16x32_bf16(A01.v, bv1, a, 0, 0, 0);
      c = __builtin_amdgcn_mfma_f32_16x16x32_bf16(A11.v, bv1, c, 0, 0, 0);
      oacc0[t] = a; oacc1[t] = c;
    }
  };

  // ---- prologue: issue sub-tiles 0,1,2 (12 loads out) ----
  issue(0, 0); issue(1, 1); issue(2, 2);

  // ---- main loop: one barrier + one counted wait per PAIR of sub-tiles ----
  // invariant at loop top: subs {i, i+1, i+2} outstanding (12 loads)
  int c0 = 0, c1 = 1, b3 = 3, b4 = 4;
  for (int p = 0; p < 30; ++p) {
    const int i = 2 * p;
    asm volatile("s_waitcnt vmcnt(4)" ::: "memory");   // subs i, i+1 landed
    __builtin_amdgcn_sched_barrier(0);
    __builtin_amdgcn_s_barrier();
    __builtin_amdgcn_sched_barrier(0);
    issue(i + 3, b3);   // buf (i-2)%5: computed last pair, barrier-confirmed
    issue(i + 4, b4);   // buf (i-1)%5: computed last pair, barrier-confirmed
    __builtin_amdgcn_s_setprio(1);
    compute(ks0 + c0 * 8192, vs0 + c0 * 8192);
    compute(ks0 + c1 * 8192, vs0 + c1 * 8192);
    __builtin_amdgcn_s_setprio(0);
    c0 += 2; if (c0 >= 5) c0 -= 5;
    c1 += 2; if (c1 >= 5) c1 -= 5;
    b3 += 2; if (b3 >= 5) b3 -= 5;
    b4 += 2; if (b4 >= 5) b4 -= 5;
  }

  // ---- peel p=30 (subs 60,61; issue 63 only) ----
  asm volatile("s_waitcnt vmcnt(4)" ::: "memory");
  __builtin_amdgcn_sched_barrier(0);
  __builtin_amdgcn_s_barrier();
  __builtin_amdgcn_sched_barrier(0);
  issue(63, b3);
  __builtin_amdgcn_s_setprio(1);
  compute(ks0 + c0 * 8192, vs0 + c0 * 8192);
  compute(ks0 + c1 * 8192, vs0 + c1 * 8192);
  __builtin_amdgcn_s_setprio(0);
  c0 += 2; if (c0 >= 5) c0 -= 5;
  c1 += 2; if (c1 >= 5) c1 -= 5;

  // ---- peel p=31 (subs 62,63; nothing in flight after wait) ----
  asm volatile("s_waitcnt vmcnt(0)" ::: "memory");
  __builtin_amdgcn_sched_barrier(0);
  __builtin_amdgcn_s_barrier();
  __builtin_amdgcn_sched_barrier(0);
  __builtin_amdgcn_s_setprio(1);
  compute(ks0 + c0 * 8192, vs0 + c0 * 8192);
  compute(ks0 + c1 * 8192, vs0 + c1 * 8192);
  __builtin_amdgcn_s_setprio(0);

  // ---- epilogue: per-half row sums, normalize, store ----
  float t0 = l0 + __shfl_xor(l0, 16);
  t0 += __shfl_xor(t0, 32);
  float t1 = l1 + __shfl_xor(l1, 16);
  t1 += __shfl_xor(t1, 32);
  const float v0i = 1.0f / t0;
  const float v1i = 1.0f / t1;

  float* ob = Og + ((size_t)b * L_ + qt * QB + wv * 32 + kb4) * D_;
#pragma unroll
  for (int j = 0; j < 4; ++j) {
    const float i0 = __shfl(v0i, kb4 + j);
    const float i1 = __shfl(v1i, kb4 + j);
    float* r0 = ob + (size_t)j * D_;
    float* r1 = r0 + 16 * D_;
#pragma unroll
    for (int t = 0; t < 4; ++t) {
      r0[t * 16 + rl] = oacc0[t][j] * i0;
      r1[t * 16 + rl] = oacc1[t][j] * i1;
    }
  }
}

// ---------------------------------------------------------------------------
// Fallback (no-workspace path).
// ---------------------------------------------------------------------------
__global__ __launch_bounds__(256) void attn_fwd_fb(
    const float* __restrict__ Qg, const float* __restrict__ Kg,
    const float* __restrict__ Vg, float* __restrict__ Og) {
  __shared__ unsigned short Ksf[KVB * D_];
  __shared__ unsigned short Vsf[KVB * D_];
  __shared__ unsigned short Psf[4][16 * KVB];

  const int tid  = threadIdx.x;
  const int wv   = tid >> 6;
  const int lane = tid & 63;
  const int rl   = lane & 15;
  const int kb   = lane >> 4;

  const int blk = blockIdx.x;
  const int b   = blk / (L_ / 64);
  const int qt  = blk % (L_ / 64);

  const float* qrow_p = Qg + ((size_t)b * L_ + qt * 64 + wv * 16 + rl) * D_;
  s16x8 aq[2];
#pragma unroll
  for (int h = 0; h < 2; ++h) {
    const float* p = qrow_p + h * 32 + kb * 8;
    f32x4 x0 = *(const f32x4*)p;
    f32x4 x1 = *(const f32x4*)(p + 4);
    s16x8 w;
#pragma unroll
    for (int i = 0; i < 4; ++i) {
      w[i]     = (short)f2bf(x0[i] * QSCALE);
      w[i + 4] = (short)f2bf(x1[i] * QSCALE);
    }
    aq[h] = w;
  }

  f32x4 oacc[4];
  float m_r[4], l_r[4];
#pragma unroll
  for (int t = 0; t < 4; ++t) oacc[t] = (f32x4){0.f, 0.f, 0.f, 0.f};
#pragma unroll
  for (int j = 0; j < 4; ++j) { m_r[j] = -3.0e38f; l_r[j] = 0.f; }

  const float* kb_p = Kg + (size_t)b * L_ * D_;
  const float* vb_p = Vg + (size_t)b * L_ * D_;
  const int skey2 = (tid >> 3) * 2;
  const int sdseg = tid & 7;

  char* ksc = (char*)Ksf;
  char* vsc = (char*)Vsf;
  char* psc = (char*)(Psf[wv]);

  for (int kv = 0; kv < L_; kv += KVB) {
    __syncthreads();
    {
      const float* kp0 = kb_p + (size_t)(kv + skey2) * D_ + sdseg * 8;
      const float* vp0 = vb_p + (size_t)(kv + skey2) * D_ + sdseg * 8;
#pragma unroll
      for (int q2 = 0; q2 < 2; ++q2) {
        const int key = skey2 + q2;
        f32x4 a0 = *(const f32x4*)(kp0 + q2 * D_);
        f32x4 a1 = *(const f32x4*)(kp0 + q2 * D_ + 4);
        s16x8 w;
#pragma unroll
        for (int i = 0; i < 4; ++i) {
          w[i]     = (short)f2bf(a0[i]);
          w[i + 4] = (short)f2bf(a1[i]);
        }
        *(s16x8*)(ksc + ((key * 128 + sdseg * 16) ^ swz(key))) = w;
      }
      f32x4 v0 = *(const f32x4*)(vp0);
      f32x4 v1 = *(const f32x4*)(vp0 + 4);
      f32x4 v2 = *(const f32x4*)(vp0 + D_);
      f32x4 v3 = *(const f32x4*)(vp0 + D_ + 4);
#pragma unroll
      for (int u = 0; u < 2; ++u) {
#pragma unroll
        for (int i = 0; i < 4; ++i) {
          const int d = sdseg * 8 + u * 4 + i;
          unsigned lo = (unsigned)f2bf(u ? v1[i] : v0[i]);
          unsigned hi = (unsigned)f2bf(u ? v3[i] : v2[i]);
          *(unsigned*)(vsc + ((d * 128 + skey2 * 2) ^ swz(d))) = lo | (hi << 16);
        }
      }
    }
    __syncthreads();

    f32x4 s[4];
#pragma unroll
    for (int t = 0; t < 4; ++t) {
      const int key  = t * 16 + rl;
      const int base = key * 128 + kb * 16;
      s16x8 b0 = *(const s16x8*)(ksc + ((base)      ^ swz(key)));
      s16x8 b1 = *(const s16x8*)(ksc + ((base + 64) ^ swz(key)));
      f32x4 acc = (f32x4){0.f, 0.f, 0.f, 0.f};
      acc = __builtin_amdgcn_mfma_f32_16x16x32_bf16(aq[0], b0, acc, 0, 0, 0);
      acc = __builtin_amdgcn_mfma_f32_16x16x32_bf16(aq[1], b1, acc, 0, 0, 0);
      s[t] = acc;
    }

    float alpha[4];
#pragma unroll
    for (int j = 0; j < 4; ++j) {
      float mx = fmaxf(fmaxf(s[0][j], s[1][j]), fmaxf(s[2][j], s[3][j]));
      mx = fmaxf(mx, __shfl_xor(mx, 1));
      mx = fmaxf(mx, __shfl_xor(mx, 2));
      mx = fmaxf(mx, __shfl_xor(mx, 4));
      mx = fmaxf(mx, __shfl_xor(mx, 8));
      const float mn = fmaxf(m_r[j], mx);
      alpha[j] = fexp2(m_r[j] - mn);
      m_r[j]   = mn;
    }

    float rs[4] = {0.f, 0.f, 0.f, 0.f};
#pragma unroll
    for (int t = 0; t < 4; ++t)
#pragma unroll
      for (int j = 0; j < 4; ++j) {
        const float p = fexp2(s[t][j] - m_r[j]);
        rs[j] += p;
        const int row = kb * 4 + j;
        *(unsigned short*)(psc + ((row * 128 + (t * 16 + rl) * 2) ^ swz(row))) = f2bf(p);
      }
#pragma unroll
    for (int j = 0; j < 4; ++j) l_r[j] = l_r[j] * alpha[j] + rs[j];

#pragma unroll
    for (int t = 0; t < 4; ++t)
#pragma unroll
      for (int j = 0; j < 4; ++j) oacc[t][j] *= alpha[j];

    s16x8 ap[2];
#pragma unroll
    for (int h = 0; h < 2; ++h) {
      const int base = rl * 128 + h * 64 + kb * 16;
      ap[h] = *(const s16x8*)(psc + (base ^ swz(rl)));
    }
#pragma unroll
    for (int t = 0; t < 4; ++t) {
      const int d    = t * 16 + rl;
      const int base = d * 128 + kb * 16;
      s16x8 bv0 = *(const s16x8*)(vsc + ((base)      ^ swz(d)));
      s16x8 bv1 = *(const s16x8*)(vsc + ((base + 64) ^ swz(d)));
      f32x4 acc = oacc[t];
      acc = __builtin_amdgcn_mfma_f32_16x16x32_bf16(ap[0], bv0, acc, 0, 0, 0);
      acc = __builtin_amdgcn_mfma_f32_16x16x32_bf16(ap[1], bv1, acc, 0, 0, 0);
      oacc[t] = acc;
    }
  }

  float inv[4];
#pragma unroll
  for (int j = 0; j < 4; ++j) {
    float r = l_r[j];
    r += __shfl_xor(r, 1);
    r += __shfl_xor(r, 2);
    r += __shfl_xor(r, 4);
    r += __shfl_xor(r, 8);
    inv[j] = 1.0f / r;
  }
  float* op = Og + ((size_t)b * L_ + qt * 64 + wv * 16 + kb * 4) * D_;
#pragma unroll
  for (int j = 0; j < 4; ++j)
#pragma unroll
    for (int t = 0; t < 4; ++t)
      op[(size_t)j * D_ + t * 16 + rl] = oacc[t][j] * inv[j];
}

extern "C" void kernel_launch(void* const* d_in, const int* in_sizes, int n_in,
                              void* d_out, int out_size, void* d_ws, size_t ws_size,
                              hipStream_t stream) {
  (void)in_sizes; (void)n_in; (void)out_size;
  const float* Q = (const float*)d_in[0];
  const float* K = (const float*)d_in[1];
  const float* V = (const float*)d_in[2];
  float* O = (float*)d_out;

  const size_t need = (size_t)2 * B_ * L_ * D_ * sizeof(unsigned short);  // 16 MB
  if (d_ws != nullptr && ws_size >= need) {
    unsigned short* Kw = (unsigned short*)d_ws;
    unsigned short* Vw = Kw + (size_t)B_ * L_ * D_;
    prep_kv4<<<dim3(2 * B_ * NT), 256, 0, stream>>>(K, V, Kw, Vw);
    attn_fwd7<<<dim3(B_ * (L_ / QB)), 256, 0, stream>>>(Q, Kw, Vw, O);
  } else {
    attn_fwd_fb<<<dim3(B_ * (L_ / 64)), 256, 0, stream>>>(Q, K, V, O);
  }
}